// Round 8
// baseline (510.605 us; speedup 1.0000x reference)
//
#include <hip/hip_runtime.h>
#include <hip/hip_bf16.h>

typedef unsigned short u16;
typedef unsigned int   u32;

using bf16x8 = __attribute__((ext_vector_type(8))) short;
using f32x4  = __attribute__((ext_vector_type(4))) float;
using f32x16 = __attribute__((ext_vector_type(16))) float;

// ---------- constants ----------
#define NB    32      // batch
#define CC    64      // in channels
#define WW_   4096    // input width
#define FF    128     // out channels
#define TAPS  9
#define NFFT  8192
#define KBINS 3597    // half_compressed
#define KB2   3616    // bins padded to 113*32 (PH table size)
#define N2    7194    // compress_fft_size
#define OW    4088    // out width
#define KP    7232    // padded 2*KBINS (mult of 64)
#define MP1   7424    // padded 2*KBINS cols for G1 (mult of 256)
#define SIG1  2048    // N*C
#define SIG2  4096    // N*F

__device__ __forceinline__ u16 f2bf(float f) {
    u32 u = __float_as_uint(f);
    return (u16)((u + 0x7FFFu + ((u >> 16) & 1u)) >> 16);
}
__device__ __forceinline__ float bf2f(u16 h) {
    return __uint_as_float(((u32)h) << 16);
}

// async global->LDS, 16B per lane; lds dest is wave-uniform base + lane*16
__device__ __forceinline__ void gload16(const void* g, void* l) {
    __builtin_amdgcn_global_load_lds(
        (const __attribute__((address_space(1))) void*)g,
        (__attribute__((address_space(3))) void*)l, 16, 0, 0);
}

// ---------- cast x to bf16 ----------
__global__ __launch_bounds__(256) void cast_x(const float* __restrict__ x,
                                              u16* __restrict__ xb, int n) {
    int stride = gridDim.x * blockDim.x;
    for (int i = blockIdx.x * blockDim.x + threadIdx.x; i < n; i += stride)
        xb[i] = f2bf(x[i]);
}

// ---------- LUTs: L1[i]=cos(2pi i/8192); L2[i]=(cos,sin)(2pi i/7194) -------
__global__ __launch_bounds__(256) void gen_luts(float* __restrict__ L1,
                                                float2* __restrict__ L2) {
    int i = blockIdx.x * 256 + threadIdx.x;
    if (i < NFFT)
        L1[i] = cosf((float)i * (6.28318530717958647692f / (float)NFFT));
    if (i < N2) {
        float th = (float)i * (6.28318530717958647692f / (float)N2);
        float2 v;
        sincosf(th, &v.y, &v.x);
        L2[i] = v;
    }
}

// ---------- Ttab[m][tau] via LUT; -sin(th) = cos(th + pi/2) = L1[r+2048] ---
__global__ __launch_bounds__(256) void gen_ttab(u16* __restrict__ T,
                                                const float* __restrict__ L1) {
    int m = blockIdx.x;              // 0..MP1-1
    int k = m >> 1;
    const int sh = (m & 1) ? 2048 : 0;
    const bool valid = (k < KBINS) && (m < 2 * KBINS);
    u32* row = (u32*)(T + (size_t)m * WW_);
    for (int p = threadIdx.x; p < WW_ / 2; p += 256) {
        u32 pack = 0;
        if (valid) {
            int r0 = (k * (2 * p) + sh) & (NFFT - 1);
            int r1 = (k * (2 * p + 1) + sh) & (NFFT - 1);
            pack = (u32)f2bf(L1[r0]) | ((u32)f2bf(L1[r1]) << 16);
        }
        row[p] = pack;
    }
}

// ---------- Dtab[t][k2] via LUT: pair (cos*sc, -sin*sc) for k=p ------------
__global__ __launch_bounds__(256) void gen_dtab(u16* __restrict__ D,
                                                const float2* __restrict__ L2) {
    int t = blockIdx.x;              // 0..4095
    u32* row = (u32*)(D + (size_t)t * KP);
    for (int p = threadIdx.x; p < KP / 2; p += 256) {
        u32 pack = 0;
        if (p < KBINS) {
            int r = (p * t) % N2;            // exact integer phase
            float2 cs = L2[r];
            float sc = (p == 0) ? (1.0f / (float)N2) : (2.0f / (float)N2);
            pack = (u32)f2bf(cs.x * sc) | ((u32)f2bf(-cs.y * sc) << 16);
        }
        row[p] = pack;
    }
}

// ---------- PH[w][b]: (cos,sin) of 2*pi*b*w/8192; 0 for b>=KBINS ----------
__global__ __launch_bounds__(256) void gen_ph(float2* __restrict__ PH) {
    int idx = blockIdx.x * 256 + threadIdx.x;
    if (idx >= TAPS * KB2) return;
    int w = idx / KB2, b = idx % KB2;
    float2 v = {0.f, 0.f};
    if (b < KBINS) {
        int r = (b * w) & (NFFT - 1);
        float th = (float)r * (6.28318530717958647692f / (float)NFFT);
        sincosf(th, &v.y, &v.x);
    }
    PH[idx] = v;
}

// ---------- filt2[f][w*64+c] = bf16(filt[f][c][w]) ----------
__global__ __launch_bounds__(256) void gen_filt2(const float* __restrict__ filt,
                                                 u16* __restrict__ F2) {
    int idx = blockIdx.x * 256 + threadIdx.x;
    if (idx >= FF * 576) return;
    int f = idx / 576, wc = idx % 576;
    int w = wc >> 6, c = wc & 63;
    F2[idx] = f2bf(filt[((size_t)f * CC + c) * TAPS + w]);
}

// ============ 256x256 MFMA GEMM, 2-barrier/K-tile, 32x32x16 grain ==========
// out[m][n] = sum_k A[m][k]*BT[n][k]; 512 thr = 8 waves (2M x 4N); BK=64;
// LDS 128KB double-buffered. Schedule identical to round 7 (2 barriers/tile,
// counted vmcnt(4), lgkm drain once). MFMA grain 32x32x16 (m119: 2495 TF
// ceiling vs 2075 for 16x16); A/B k-permutation cancels between operands;
// C/D layout col=lane&31, row=(reg&3)+8*(reg>>2)+4*(lane>>5)  [m74/m101].
#define MFMA_Q32(AS, BS, MH, NH)                                            \
    __builtin_amdgcn_s_setprio(1);                                          \
    _Pragma("unroll")                                                       \
    for (int ks = 0; ks < 4; ks++)                                          \
        _Pragma("unroll")                                                   \
        for (int mt = 0; mt < 2; mt++)                                      \
            acc[(MH)*2 + mt][NH] = __builtin_amdgcn_mfma_f32_32x32x16_bf16( \
                AS[mt][ks], BS[ks], acc[(MH)*2 + mt][NH], 0, 0, 0);         \
    __builtin_amdgcn_s_setprio(0);

#define LOAD_A32(AS, MH, BUF)                                               \
    _Pragma("unroll")                                                       \
    for (int mt = 0; mt < 2; mt++)                                          \
        _Pragma("unroll")                                                   \
        for (int ks = 0; ks < 4; ks++) {                                    \
            int row_ = wr * 128 + (MH)*64 + mt * 32 + r32;                  \
            AS[mt][ks] = *(const bf16x8*)(smem + (BUF)*32768 +              \
                          row_ * 128 + ((ks * 32 + hk32) ^ askew));         \
        }

#define LOAD_B32(BS, NH, BUF)                                               \
    _Pragma("unroll")                                                       \
    for (int ks = 0; ks < 4; ks++) {                                        \
        int row_ = wc * 64 + (NH)*32 + r32;                                 \
        BS[ks] = *(const bf16x8*)(smem + 65536 + (BUF)*32768 +              \
                      row_ * 128 + ((ks * 32 + hk32) ^ askew));             \
    }

#define STAGE(Q, R, BUF)                                                    \
    {                                                                       \
        const u16* g_ = ((R) < 2) ? gA : gB;                                \
        size_t ro_ = (size_t)((R)&1) * 128 * K;                             \
        int lb_ = (((R) < 2) ? 0 : 65536) + (BUF)*32768 +                   \
                  (((R)&1) * 128 + wid * 16) * 128;                         \
        gload16(g_ + ro_ + (Q)*64, smem + lb_);                             \
        gload16(g_ + ro_ + (size_t)8 * K + (Q)*64, smem + lb_ + 1024);      \
    }

#define BAR() __builtin_amdgcn_s_barrier()

template <int MODE>
__global__ __launch_bounds__(512, 1) void gemm256(const u16* __restrict__ A,
                                                  const u16* __restrict__ B,
                                                  int K, int gridN,
                                                  void* __restrict__ Out,
                                                  int ldo,
                                                  const float* __restrict__ bias) {
    extern __shared__ char smem[];   // [A b0|A b1|B b0|B b1] x 32KB
    const int tid = threadIdx.x;
    const int lane = tid & 63, wid = tid >> 6;
    const int wr = wid >> 2, wc = wid & 3;
    const int r32  = lane & 31;          // fragment row
    const int hk32 = (lane >> 5) << 4;   // k-half byte offset
    const int askew = (lane & 7) << 4;   // == (row&7)<<4 since row = ..+r32

    const int nwg = (int)gridDim.x, cpx = nwg >> 3;
    const int bid = (int)blockIdx.x;
    const int wg = (bid & 7) * cpx + (bid >> 3);
    const int tm = wg / gridN, tn = wg % gridN;
    const int NT = K >> 6;

    f32x16 acc[4][2];
#pragma unroll
    for (int i = 0; i < 4; i++)
#pragma unroll
        for (int j = 0; j < 2; j++) acc[i][j] = (f32x16)(0.f);

    const int srow = lane >> 3;
    const int scol = ((lane & 7) ^ srow) * 8;
    const u16* gA = A + (size_t)(tm * 256 + wid * 16 + srow) * K + scol;
    const u16* gB = B + (size_t)(tn * 256 + wid * 16 + srow) * K + scol;

    // prologue: full tile0 -> buf0, A(1) -> buf1; leaves A(1) in flight
    STAGE(0, 0, 0) STAGE(0, 1, 0) STAGE(0, 2, 0) STAGE(0, 3, 0)
    STAGE(1, 0, 1) STAGE(1, 1, 1)
    asm volatile("s_waitcnt vmcnt(4)" ::: "memory");
    BAR();

    bf16x8 a0[2][4], a1[2][4], b0[4], b1[4];
    for (int t = 0; t < NT; ++t) {
        const int cur = t & 1, nxt = cur ^ 1;
        LOAD_A32(a0, 0, cur)
        LOAD_B32(b0, 0, cur)
        LOAD_B32(b1, 1, cur)
        if (t + 1 < NT) { STAGE(t + 1, 2, nxt) STAGE(t + 1, 3, nxt) }
        MFMA_Q32(a0, b0, 0, 0)
        LOAD_A32(a1, 1, cur)        // issued under q01's MFMA shadow
        MFMA_Q32(a0, b1, 0, 1)
        asm volatile("s_waitcnt lgkmcnt(0)" ::: "memory");  // cur-A reads done
        __builtin_amdgcn_sched_barrier(0);
        BAR();                       // #1: cur-A region now dead block-wide
        if (t + 2 < NT) { STAGE(t + 2, 0, cur) STAGE(t + 2, 1, cur) }
        MFMA_Q32(a1, b1, 1, 1)
        MFMA_Q32(a1, b0, 1, 0)
        if (t + 2 < NT) {
            asm volatile("s_waitcnt vmcnt(4)" ::: "memory");  // A(t+1),B(t+1) in
        } else if (t + 1 < NT) {
            asm volatile("s_waitcnt vmcnt(0)" ::: "memory");  // drain for last
        }
        BAR();                       // #2: publish nxt
    }

    // epilogue: C/D 32x32 layout col=lane&31, row=(reg&3)+8*(reg>>2)+4*(lane>>5)
#pragma unroll
    for (int i = 0; i < 4; i++) {
#pragma unroll
        for (int n = 0; n < 2; n++) {
            int colb = tn * 256 + wc * 64 + n * 32 + r32;
            int rowb = tm * 256 + wr * 128 + i * 32 + ((lane >> 5) << 2);
#pragma unroll
            for (int reg = 0; reg < 16; reg++) {
                int grow = rowb + (reg & 3) + 8 * (reg >> 2);
                if (MODE == 0) {
                    ((u16*)Out)[(size_t)grow * ldo + colb] = f2bf(acc[i][n][reg]);
                } else {
                    if (colb < OW) {
                        ((float*)Out)[(size_t)grow * OW + colb] =
                            acc[i][n][reg] + bias[grow & 127];
                    }
                }
            }
        }
    }
}

// ============ step_c2: spectral contraction as one MFMA GEMM over (c,w) ====
// spec[n,f,k] = sum_{c,w} filt[f,c,w] * (X[n,c,k] * e^{i*2pi*k*w/8192})
#define ZBUILD(T, BUF)                                                      \
    {                                                                       \
        float2 ph = lph[(T) * 32 + zk];                                     \
        bf16x8 zr, zi;                                                      \
        _Pragma("unroll")                                                   \
        for (int j = 0; j < 8; j++) {                                       \
            int c_ = zcb * 8 + j;                                           \
            u32 xv = lxu[c_ * 32 +                                          \
                         (((zk >> 2) ^ j ^ zcb) << 2) + (zk & 3)];          \
            float xr = bf2f((u16)(xv & 0xffff));                            \
            float xi = bf2f((u16)(xv >> 16));                               \
            zr[j] = (short)f2bf(xr * ph.x - xi * ph.y);                     \
            zi[j] = (short)f2bf(xi * ph.x + xr * ph.y);                     \
        }                                                                   \
        int rR = 2 * zk, rI = 2 * zk + 1;                                   \
        *(bf16x8*)(lzc + (BUF)*8192 + rR * 128 + ((zcb ^ (rR & 7)) << 4)) = zr; \
        *(bf16x8*)(lzc + (BUF)*8192 + rI * 128 + ((zcb ^ (rI & 7)) << 4)) = zi; \
    }

#define STAGE_A2(T, BUF)                                                    \
    _Pragma("unroll")                                                       \
    for (int j = 0; j < 4; j++) {                                           \
        gload16(F2 + (size_t)(wid * 32 + j * 8 + (lane >> 3)) * 576 +       \
                    (T) * 64 + (((lane & 7) ^ (lane >> 3)) * 8),            \
                lac + (BUF)*16384 + (wid * 32 + j * 8) * 128);              \
    }

__global__ __launch_bounds__(256, 2) void step_c2(const u16* __restrict__ XF_,
                                                  const u16* __restrict__ F2,
                                                  const float2* __restrict__ PH,
                                                  u16* __restrict__ S) {
    __shared__ u16 la[2 * 128 * 64];    // 32 KB  A double-buffer
    __shared__ u16 lz[2 * 64 * 64];     // 16 KB  Z double-buffer
    __shared__ u32 lx[64 * 32];         // 8 KB   X tile (packed complex, swz)
    __shared__ float2 lph[TAPS * 32];   // 2.25 KB
    const int tid = threadIdx.x;
    const int lane = tid & 63, wid = tid >> 6;
    const int kt = blockIdx.x, n = blockIdx.y;
    const int fr = lane & 15;
    const int hk = (lane >> 4) << 4;
    const int askew = (fr & 7) << 4;
    char* lac = (char*)la;
    char* lzc = (char*)lz;
    char* lxc = (char*)lx;
    const u32* lxu = lx;
    const int zk = tid >> 3;            // 0..31 local bin
    const int zcb = tid & 7;            // c-block of 8

    // stage X tile: rows c = wid*16+j*8+(lane>>3), 16B col16 ^= (c&7)^(c>>3)
#pragma unroll
    for (int j = 0; j < 2; j++) {
        int c_ = wid * 16 + j * 8 + (lane >> 3);
        gload16(XF_ + (size_t)(n * 64 + c_) * MP1 + kt * 64 +
                    (((lane & 7) ^ (lane >> 3) ^ (wid * 2 + j)) * 8),
                lxc + (wid * 16 + j * 8) * 128);
    }
    // lph: 288 entries > 256 threads -> grid-stride
    for (int i = tid; i < TAPS * 32; i += 256) {
        int w_ = i >> 5, b_ = i & 31;
        lph[i] = PH[w_ * KB2 + kt * 32 + b_];
    }
    __syncthreads();

    f32x4 acc[2][4];
#pragma unroll
    for (int i = 0; i < 2; i++)
#pragma unroll
        for (int j = 0; j < 4; j++) acc[i][j] = (f32x4){0.f, 0.f, 0.f, 0.f};

    ZBUILD(0, 0)
    STAGE_A2(0, 0)
    __syncthreads();

    bf16x8 af[2][2], bfr[4][2];
    for (int t = 0; t < TAPS; ++t) {
        const int cur = t & 1, nxt = cur ^ 1;
#pragma unroll
        for (int m2 = 0; m2 < 2; m2++)
#pragma unroll
            for (int kk = 0; kk < 2; kk++) {
                int row_ = wid * 32 + m2 * 16 + fr;
                af[m2][kk] = *(const bf16x8*)(lac + cur * 16384 + row_ * 128 +
                                              ((kk * 64 + hk) ^ askew));
            }
#pragma unroll
        for (int n4 = 0; n4 < 4; n4++)
#pragma unroll
            for (int kk = 0; kk < 2; kk++) {
                int row_ = n4 * 16 + fr;
                bfr[n4][kk] = *(const bf16x8*)(lzc + cur * 8192 + row_ * 128 +
                                               ((kk * 64 + hk) ^ askew));
            }
        if (t + 1 < TAPS) {
            ZBUILD(t + 1, nxt)
            STAGE_A2(t + 1, nxt)
        }
        __builtin_amdgcn_s_setprio(1);
#pragma unroll
        for (int kk = 0; kk < 2; kk++)
#pragma unroll
            for (int m2 = 0; m2 < 2; m2++)
#pragma unroll
                for (int n4 = 0; n4 < 4; n4++)
                    acc[m2][n4] = __builtin_amdgcn_mfma_f32_16x16x32_bf16(
                        af[m2][kk], bfr[n4][kk], acc[m2][n4], 0, 0, 0);
        __builtin_amdgcn_s_setprio(0);
        __syncthreads();
    }

    // epilogue: S[n*128+f][kt*64+col], C/D layout col=lane&15,row=(lane>>4)*4+j
#pragma unroll
    for (int m2 = 0; m2 < 2; m2++) {
#pragma unroll
        for (int n4 = 0; n4 < 4; n4++) {
            int colk = kt * 64 + n4 * 16 + fr;
            int f0 = wid * 32 + m2 * 16 + ((lane >> 4) << 2);
#pragma unroll
            for (int j = 0; j < 4; j++) {
                int sig2 = n * 128 + f0 + j;
                S[(size_t)sig2 * KP + colk] = f2bf(acc[m2][n4][j]);
            }
        }
    }
}

// ---------- launch ----------
extern "C" void kernel_launch(void* const* d_in, const int* in_sizes, int n_in,
                              void* d_out, int out_size, void* d_ws, size_t ws_size,
                              hipStream_t stream) {
    (void)in_sizes; (void)n_in; (void)out_size; (void)ws_size;
    const float* x    = (const float*)d_in[0];
    const float* filt = (const float*)d_in[1];
    const float* bias = (const float*)d_in[2];

    char* ws = (char*)d_ws;
    u16* TT = (u16*)(ws);                  // 60,817,408 B (Ttab, then Dtab)
    u16* XF = (u16*)(ws + 60817408);       // 2048 x 7424 bf16 = 30,408,704
    u16* XB = (u16*)(ws + 91226112);       // 2048 x 4096 bf16 = 16,777,216
    u16* S  = (u16*)(ws + 108003328);      // 4096 x 7232 bf16 = 59,244,544
    u16* F2 = (u16*)(ws + 167247872);      // 128 x 576 bf16   = 147,456
    float2* PH = (float2*)(ws + 167395328); // 9 x 3616 float2 = 260,352
    float*  L1 = (float*)(ws + 167655680);  // 8192 f32        = 32,768
    float2* L2 = (float2*)(ws + 167688448); // 7194 float2     = 57,552
    // total: 167,746,000 B

    hipFuncSetAttribute(reinterpret_cast<const void*>(gemm256<0>),
                        hipFuncAttributeMaxDynamicSharedMemorySize, 131072);
    hipFuncSetAttribute(reinterpret_cast<const void*>(gemm256<1>),
                        hipFuncAttributeMaxDynamicSharedMemorySize, 131072);

    cast_x<<<4096, 256, 0, stream>>>(x, XB, NB * CC * WW_);
    gen_luts<<<(NFFT + 255) / 256, 256, 0, stream>>>(L1, L2);
    gen_ph<<<(TAPS * KB2 + 255) / 256, 256, 0, stream>>>(PH);
    gen_filt2<<<(FF * 576 + 255) / 256, 256, 0, stream>>>(filt, F2);
    gen_ttab<<<MP1, 256, 0, stream>>>(TT, L1);
    gemm256<0><<<8 * (MP1 / 256), 512, 131072, stream>>>(
        XB, TT, WW_, MP1 / 256, XF, MP1, nullptr);
    gen_dtab<<<SIG2, 256, 0, stream>>>(TT, L2);   // overwrites Ttab (dead)
    step_c2<<<dim3(KP / 64, NB), 256, 0, stream>>>(XF, F2, PH, S);
    gemm256<1><<<16 * 16, 512, 131072, stream>>>(
        S, TT, KP, 16, d_out, OW, bias);
}

// Round 9
// 507.012 us; speedup vs baseline: 1.0071x; 1.0071x over previous
//
#include <hip/hip_runtime.h>
#include <hip/hip_bf16.h>

typedef unsigned short u16;
typedef unsigned int   u32;

using bf16x8 = __attribute__((ext_vector_type(8))) short;
using f32x4  = __attribute__((ext_vector_type(4))) float;
using f32x16 = __attribute__((ext_vector_type(16))) float;

// ---------- constants ----------
#define NB    32      // batch
#define CC    64      // in channels
#define WW_   4096    // input width
#define FF    128     // out channels
#define TAPS  9
#define NFFT  8192
#define KBINS 3597    // half_compressed
#define KB2   3616    // bins padded to 113*32 (PH table size)
#define N2    7194    // compress_fft_size
#define OW    4088    // out width
#define KP    7232    // padded 2*KBINS (mult of 64)
#define MP1   7424    // padded 2*KBINS cols for G1 (mult of 256)
#define SIG1  2048    // N*C
#define SIG2  4096    // N*F

__device__ __forceinline__ u16 f2bf(float f) {
    u32 u = __float_as_uint(f);
    return (u16)((u + 0x7FFFu + ((u >> 16) & 1u)) >> 16);
}
__device__ __forceinline__ float bf2f(u16 h) {
    return __uint_as_float(((u32)h) << 16);
}

// async global->LDS, 16B per lane; lds dest is wave-uniform base + lane*16
__device__ __forceinline__ void gload16(const void* g, void* l) {
    __builtin_amdgcn_global_load_lds(
        (const __attribute__((address_space(1))) void*)g,
        (__attribute__((address_space(3))) void*)l, 16, 0, 0);
}

// ---------- cast x to bf16 ----------
__global__ __launch_bounds__(256) void cast_x(const float* __restrict__ x,
                                              u16* __restrict__ xb, int n) {
    int stride = gridDim.x * blockDim.x;
    for (int i = blockIdx.x * blockDim.x + threadIdx.x; i < n; i += stride)
        xb[i] = f2bf(x[i]);
}

// ---------- LUTs: L1[i]=cos(2pi i/8192); L2[i]=(cos,sin)(2pi i/7194) -------
__global__ __launch_bounds__(256) void gen_luts(float* __restrict__ L1,
                                                float2* __restrict__ L2) {
    int i = blockIdx.x * 256 + threadIdx.x;
    if (i < NFFT)
        L1[i] = cosf((float)i * (6.28318530717958647692f / (float)NFFT));
    if (i < N2) {
        float th = (float)i * (6.28318530717958647692f / (float)N2);
        float2 v;
        sincosf(th, &v.y, &v.x);
        L2[i] = v;
    }
}

// ---------- Ttab[m][tau] via LUT; -sin(th) = cos(th + pi/2) = L1[r+2048] ---
__global__ __launch_bounds__(256) void gen_ttab(u16* __restrict__ T,
                                                const float* __restrict__ L1) {
    int m = blockIdx.x;              // 0..MP1-1
    int k = m >> 1;
    const int sh = (m & 1) ? 2048 : 0;
    const bool valid = (k < KBINS) && (m < 2 * KBINS);
    u32* row = (u32*)(T + (size_t)m * WW_);
    for (int p = threadIdx.x; p < WW_ / 2; p += 256) {
        u32 pack = 0;
        if (valid) {
            int r0 = (k * (2 * p) + sh) & (NFFT - 1);
            int r1 = (k * (2 * p + 1) + sh) & (NFFT - 1);
            pack = (u32)f2bf(L1[r0]) | ((u32)f2bf(L1[r1]) << 16);
        }
        row[p] = pack;
    }
}

// ---------- Dtab[t][k2] via LUT: pair (cos*sc, -sin*sc) for k=p ------------
__global__ __launch_bounds__(256) void gen_dtab(u16* __restrict__ D,
                                                const float2* __restrict__ L2) {
    int t = blockIdx.x;              // 0..4095
    u32* row = (u32*)(D + (size_t)t * KP);
    for (int p = threadIdx.x; p < KP / 2; p += 256) {
        u32 pack = 0;
        if (p < KBINS) {
            int r = (p * t) % N2;            // exact integer phase
            float2 cs = L2[r];
            float sc = (p == 0) ? (1.0f / (float)N2) : (2.0f / (float)N2);
            pack = (u32)f2bf(cs.x * sc) | ((u32)f2bf(-cs.y * sc) << 16);
        }
        row[p] = pack;
    }
}

// ---------- PH[w][b]: (cos,sin) of 2*pi*b*w/8192; 0 for b>=KBINS ----------
__global__ __launch_bounds__(256) void gen_ph(float2* __restrict__ PH) {
    int idx = blockIdx.x * 256 + threadIdx.x;
    if (idx >= TAPS * KB2) return;
    int w = idx / KB2, b = idx % KB2;
    float2 v = {0.f, 0.f};
    if (b < KBINS) {
        int r = (b * w) & (NFFT - 1);
        float th = (float)r * (6.28318530717958647692f / (float)NFFT);
        sincosf(th, &v.y, &v.x);
    }
    PH[idx] = v;
}

// ---------- filt2[f][w*64+c] = bf16(filt[f][c][w]) ----------
__global__ __launch_bounds__(256) void gen_filt2(const float* __restrict__ filt,
                                                 u16* __restrict__ F2) {
    int idx = blockIdx.x * 256 + threadIdx.x;
    if (idx >= FF * 576) return;
    int f = idx / 576, wc = idx % 576;
    int w = wc >> 6, c = wc & 63;
    F2[idx] = f2bf(filt[((size_t)f * CC + c) * TAPS + w]);
}

// ============ 256x256 MFMA GEMM, 2-barrier/K-tile, 32x32x16 grain ==========
// Swizzle key (both sides): key(row) = (row&7) ^ (((row>>3)&3)<<1).
// Read: col16 ^= key -> 8 distinct slots per 8-lane phase group at any
// stride (fixes round-8's 4-way conflict: 32-row reads only spanned 2
// column slots with the old (row&7) key). Stage: global source col16
// pre-XOR'd with the same key (linear LDS dest, rule #21).
#define MFMA_Q32(AS, BS, MH, NH)                                            \
    __builtin_amdgcn_s_setprio(1);                                          \
    _Pragma("unroll")                                                       \
    for (int ks = 0; ks < 4; ks++)                                          \
        _Pragma("unroll")                                                   \
        for (int mt = 0; mt < 2; mt++)                                      \
            acc[(MH)*2 + mt][NH] = __builtin_amdgcn_mfma_f32_32x32x16_bf16( \
                AS[mt][ks], BS[ks], acc[(MH)*2 + mt][NH], 0, 0, 0);         \
    __builtin_amdgcn_s_setprio(0);

#define LOAD_A32(AS, MH, BUF)                                               \
    _Pragma("unroll")                                                       \
    for (int mt = 0; mt < 2; mt++)                                          \
        _Pragma("unroll")                                                   \
        for (int ks = 0; ks < 4; ks++) {                                    \
            int row_ = wr * 128 + (MH)*64 + mt * 32 + r32;                  \
            AS[mt][ks] = *(const bf16x8*)(smem + (BUF)*32768 +              \
                          row_ * 128 + ((ks * 32 + hk32) ^ askw2));         \
        }

#define LOAD_B32(BS, NH, BUF)                                               \
    _Pragma("unroll")                                                       \
    for (int ks = 0; ks < 4; ks++) {                                        \
        int row_ = wc * 64 + (NH)*32 + r32;                                 \
        BS[ks] = *(const bf16x8*)(smem + 65536 + (BUF)*32768 +              \
                      row_ * 128 + ((ks * 32 + hk32) ^ askw2));             \
    }

// stage half-tile R (0:A rows0-127,1:A rows128-255,2:B0,3:B1) of K-tile Q
#define STAGE(Q, R, BUF)                                                    \
    {                                                                       \
        const u16* g_ = ((R) < 2) ? gA : gB;                                \
        size_t ro_ = (size_t)((R)&1) * 128 * K;                             \
        int lb_ = (((R) < 2) ? 0 : 65536) + (BUF)*32768 +                   \
                  (((R)&1) * 128 + wid * 16) * 128;                         \
        int c0_ = ((wid * 2 + 0) & 3) << 1;                                 \
        int c1_ = ((wid * 2 + 1) & 3) << 1;                                 \
        gload16(g_ + ro_ + (Q)*64 + ((sc8 ^ c0_) << 3), smem + lb_);        \
        gload16(g_ + ro_ + (size_t)8 * K + (Q)*64 + ((sc8 ^ c1_) << 3),     \
                smem + lb_ + 1024);                                         \
    }

#define BAR() __builtin_amdgcn_s_barrier()

template <int MODE>
__global__ __launch_bounds__(512, 1) void gemm256(const u16* __restrict__ A,
                                                  const u16* __restrict__ B,
                                                  int K, int gridN,
                                                  void* __restrict__ Out,
                                                  int ldo,
                                                  const float* __restrict__ bias) {
    extern __shared__ char smem[];   // [A b0|A b1|B b0|B b1] x 32KB
    const int tid = threadIdx.x;
    const int lane = tid & 63, wid = tid >> 6;
    const int wr = wid >> 2, wc = wid & 3;
    const int r32  = lane & 31;          // fragment row
    const int hk32 = (lane >> 5) << 4;   // k-half byte offset
    // read-side swizzle key: (row&7)=lane&7, (row>>3)&3=(lane>>3)&3
    const int askw2 = (((lane & 7) ^ (((lane >> 3) & 3) << 1)) << 4);

    const int nwg = (int)gridDim.x, cpx = nwg >> 3;
    const int bid = (int)blockIdx.x;
    const int wg = (bid & 7) * cpx + (bid >> 3);
    const int tm = wg / gridN, tn = wg % gridN;
    const int NT = K >> 6;

    f32x16 acc[4][2];
#pragma unroll
    for (int i = 0; i < 4; i++)
#pragma unroll
        for (int j = 0; j < 2; j++) acc[i][j] = (f32x16)(0.f);

    // staging: row = base + srow (+8 for 2nd gload); src col16 = (lane&7)^key
    const int srow = lane >> 3;
    const int sc8  = (lane & 7) ^ srow;    // ^ c_j applied per call in STAGE
    const u16* gA = A + (size_t)(tm * 256 + wid * 16 + srow) * K;
    const u16* gB = B + (size_t)(tn * 256 + wid * 16 + srow) * K;

    // prologue: full tile0 -> buf0, A(1) -> buf1; leaves A(1) in flight
    STAGE(0, 0, 0) STAGE(0, 1, 0) STAGE(0, 2, 0) STAGE(0, 3, 0)
    STAGE(1, 0, 1) STAGE(1, 1, 1)
    asm volatile("s_waitcnt vmcnt(4)" ::: "memory");
    BAR();

    bf16x8 a0[2][4], a1[2][4], b0[4], b1[4];
    for (int t = 0; t < NT; ++t) {
        const int cur = t & 1, nxt = cur ^ 1;
        LOAD_A32(a0, 0, cur)
        LOAD_B32(b0, 0, cur)
        LOAD_B32(b1, 1, cur)
        if (t + 1 < NT) { STAGE(t + 1, 2, nxt) STAGE(t + 1, 3, nxt) }
        MFMA_Q32(a0, b0, 0, 0)
        LOAD_A32(a1, 1, cur)        // issued under q01's MFMA shadow
        MFMA_Q32(a0, b1, 0, 1)
        asm volatile("s_waitcnt lgkmcnt(0)" ::: "memory");  // cur-A reads done
        __builtin_amdgcn_sched_barrier(0);
        BAR();                       // #1: cur-A region now dead block-wide
        if (t + 2 < NT) { STAGE(t + 2, 0, cur) STAGE(t + 2, 1, cur) }
        MFMA_Q32(a1, b1, 1, 1)
        MFMA_Q32(a1, b0, 1, 0)
        if (t + 2 < NT) {
            asm volatile("s_waitcnt vmcnt(4)" ::: "memory");  // A(t+1),B(t+1) in
        } else if (t + 1 < NT) {
            asm volatile("s_waitcnt vmcnt(0)" ::: "memory");  // drain for last
        }
        BAR();                       // #2: publish nxt
    }

    // epilogue: C/D 32x32 layout col=lane&31, row=(reg&3)+8*(reg>>2)+4*(lane>>5)
#pragma unroll
    for (int i = 0; i < 4; i++) {
#pragma unroll
        for (int n = 0; n < 2; n++) {
            int colb = tn * 256 + wc * 64 + n * 32 + r32;
            int rowb = tm * 256 + wr * 128 + i * 32 + ((lane >> 5) << 2);
#pragma unroll
            for (int reg = 0; reg < 16; reg++) {
                int grow = rowb + (reg & 3) + 8 * (reg >> 2);
                if (MODE == 0) {
                    ((u16*)Out)[(size_t)grow * ldo + colb] = f2bf(acc[i][n][reg]);
                } else {
                    if (colb < OW) {
                        ((float*)Out)[(size_t)grow * OW + colb] =
                            acc[i][n][reg] + bias[grow & 127];
                    }
                }
            }
        }
    }
}

// ============ step_c2: spectral contraction as one MFMA GEMM over (c,w) ====
// spec[n,f,k] = sum_{c,w} filt[f,c,w] * (X[n,c,k] * e^{i*2pi*k*w/8192})
#define ZBUILD(T, BUF)                                                      \
    {                                                                       \
        float2 ph = lph[(T) * 32 + zk];                                     \
        bf16x8 zr, zi;                                                      \
        _Pragma("unroll")                                                   \
        for (int j = 0; j < 8; j++) {                                       \
            int c_ = zcb * 8 + j;                                           \
            u32 xv = lxu[c_ * 32 +                                          \
                         (((zk >> 2) ^ j ^ zcb) << 2) + (zk & 3)];          \
            float xr = bf2f((u16)(xv & 0xffff));                            \
            float xi = bf2f((u16)(xv >> 16));                               \
            zr[j] = (short)f2bf(xr * ph.x - xi * ph.y);                     \
            zi[j] = (short)f2bf(xi * ph.x + xr * ph.y);                     \
        }                                                                   \
        int rR = 2 * zk, rI = 2 * zk + 1;                                   \
        *(bf16x8*)(lzc + (BUF)*8192 + rR * 128 + ((zcb ^ (rR & 7)) << 4)) = zr; \
        *(bf16x8*)(lzc + (BUF)*8192 + rI * 128 + ((zcb ^ (rI & 7)) << 4)) = zi; \
    }

#define STAGE_A2(T, BUF)                                                    \
    _Pragma("unroll")                                                       \
    for (int j = 0; j < 4; j++) {                                           \
        gload16(F2 + (size_t)(wid * 32 + j * 8 + (lane >> 3)) * 576 +       \
                    (T) * 64 + (((lane & 7) ^ (lane >> 3)) * 8),            \
                lac + (BUF)*16384 + (wid * 32 + j * 8) * 128);              \
    }

__global__ __launch_bounds__(256, 2) void step_c2(const u16* __restrict__ XF_,
                                                  const u16* __restrict__ F2,
                                                  const float2* __restrict__ PH,
                                                  u16* __restrict__ S) {
    __shared__ u16 la[2 * 128 * 64];    // 32 KB  A double-buffer
    __shared__ u16 lz[2 * 64 * 64];     // 16 KB  Z double-buffer
    __shared__ u32 lx[64 * 32];         // 8 KB   X tile (packed complex, swz)
    __shared__ float2 lph[TAPS * 32];   // 2.25 KB
    const int tid = threadIdx.x;
    const int lane = tid & 63, wid = tid >> 6;
    const int kt = blockIdx.x, n = blockIdx.y;
    const int fr = lane & 15;
    const int hk = (lane >> 4) << 4;
    const int askew = (fr & 7) << 4;
    char* lac = (char*)la;
    char* lzc = (char*)lz;
    char* lxc = (char*)lx;
    const u32* lxu = lx;
    const int zk = tid >> 3;            // 0..31 local bin
    const int zcb = tid & 7;            // c-block of 8

    // stage X tile: rows c = wid*16+j*8+(lane>>3), 16B col16 ^= (c&7)^(c>>3)
#pragma unroll
    for (int j = 0; j < 2; j++) {
        int c_ = wid * 16 + j * 8 + (lane >> 3);
        gload16(XF_ + (size_t)(n * 64 + c_) * MP1 + kt * 64 +
                    (((lane & 7) ^ (lane >> 3) ^ (wid * 2 + j)) * 8),
                lxc + (wid * 16 + j * 8) * 128);
    }
    // lph: 288 entries > 256 threads -> grid-stride
    for (int i = tid; i < TAPS * 32; i += 256) {
        int w_ = i >> 5, b_ = i & 31;
        lph[i] = PH[w_ * KB2 + kt * 32 + b_];
    }
    __syncthreads();

    f32x4 acc[2][4];
#pragma unroll
    for (int i = 0; i < 2; i++)
#pragma unroll
        for (int j = 0; j < 4; j++) acc[i][j] = (f32x4){0.f, 0.f, 0.f, 0.f};

    ZBUILD(0, 0)
    STAGE_A2(0, 0)
    __syncthreads();

    bf16x8 af[2][2], bfr[4][2];
    for (int t = 0; t < TAPS; ++t) {
        const int cur = t & 1, nxt = cur ^ 1;
#pragma unroll
        for (int m2 = 0; m2 < 2; m2++)
#pragma unroll
            for (int kk = 0; kk < 2; kk++) {
                int row_ = wid * 32 + m2 * 16 + fr;
                af[m2][kk] = *(const bf16x8*)(lac + cur * 16384 + row_ * 128 +
                                              ((kk * 64 + hk) ^ askew));
            }
#pragma unroll
        for (int n4 = 0; n4 < 4; n4++)
#pragma unroll
            for (int kk = 0; kk < 2; kk++) {
                int row_ = n4 * 16 + fr;
                bfr[n4][kk] = *(const bf16x8*)(lzc + cur * 8192 + row_ * 128 +
                                               ((kk * 64 + hk) ^ askew));
            }
        if (t + 1 < TAPS) {
            ZBUILD(t + 1, nxt)
            STAGE_A2(t + 1, nxt)
        }
        __builtin_amdgcn_s_setprio(1);
#pragma unroll
        for (int kk = 0; kk < 2; kk++)
#pragma unroll
            for (int m2 = 0; m2 < 2; m2++)
#pragma unroll
                for (int n4 = 0; n4 < 4; n4++)
                    acc[m2][n4] = __builtin_amdgcn_mfma_f32_16x16x32_bf16(
                        af[m2][kk], bfr[n4][kk], acc[m2][n4], 0, 0, 0);
        __builtin_amdgcn_s_setprio(0);
        __syncthreads();
    }

    // epilogue: S[n*128+f][kt*64+col], C/D layout col=lane&15,row=(lane>>4)*4+j
#pragma unroll
    for (int m2 = 0; m2 < 2; m2++) {
#pragma unroll
        for (int n4 = 0; n4 < 4; n4++) {
            int colk = kt * 64 + n4 * 16 + fr;
            int f0 = wid * 32 + m2 * 16 + ((lane >> 4) << 2);
#pragma unroll
            for (int j = 0; j < 4; j++) {
                int sig2 = n * 128 + f0 + j;
                S[(size_t)sig2 * KP + colk] = f2bf(acc[m2][n4][j]);
            }
        }
    }
}

// ---------- launch ----------
extern "C" void kernel_launch(void* const* d_in, const int* in_sizes, int n_in,
                              void* d_out, int out_size, void* d_ws, size_t ws_size,
                              hipStream_t stream) {
    (void)in_sizes; (void)n_in; (void)out_size; (void)ws_size;
    const float* x    = (const float*)d_in[0];
    const float* filt = (const float*)d_in[1];
    const float* bias = (const float*)d_in[2];

    char* ws = (char*)d_ws;
    u16* TT = (u16*)(ws);                  // 60,817,408 B (Ttab, then Dtab)
    u16* XF = (u16*)(ws + 60817408);       // 2048 x 7424 bf16 = 30,408,704
    u16* XB = (u16*)(ws + 91226112);       // 2048 x 4096 bf16 = 16,777,216
    u16* S  = (u16*)(ws + 108003328);      // 4096 x 7232 bf16 = 59,244,544
    u16* F2 = (u16*)(ws + 167247872);      // 128 x 576 bf16   = 147,456
    float2* PH = (float2*)(ws + 167395328); // 9 x 3616 float2 = 260,352
    float*  L1 = (float*)(ws + 167655680);  // 8192 f32        = 32,768
    float2* L2 = (float2*)(ws + 167688448); // 7194 float2     = 57,552
    // total: 167,746,000 B

    hipFuncSetAttribute(reinterpret_cast<const void*>(gemm256<0>),
                        hipFuncAttributeMaxDynamicSharedMemorySize, 131072);
    hipFuncSetAttribute(reinterpret_cast<const void*>(gemm256<1>),
                        hipFuncAttributeMaxDynamicSharedMemorySize, 131072);

    cast_x<<<4096, 256, 0, stream>>>(x, XB, NB * CC * WW_);
    gen_luts<<<(NFFT + 255) / 256, 256, 0, stream>>>(L1, L2);
    gen_ph<<<(TAPS * KB2 + 255) / 256, 256, 0, stream>>>(PH);
    gen_filt2<<<(FF * 576 + 255) / 256, 256, 0, stream>>>(filt, F2);
    gen_ttab<<<MP1, 256, 0, stream>>>(TT, L1);
    gemm256<0><<<8 * (MP1 / 256), 512, 131072, stream>>>(
        XB, TT, WW_, MP1 / 256, XF, MP1, nullptr);
    gen_dtab<<<SIG2, 256, 0, stream>>>(TT, L2);   // overwrites Ttab (dead)
    step_c2<<<dim3(KP / 64, NB), 256, 0, stream>>>(XF, F2, PH, S);
    gemm256<1><<<16 * 16, 512, 131072, stream>>>(
        S, TT, KP, 16, d_out, OW, bias);
}

// Round 10
// 462.216 us; speedup vs baseline: 1.1047x; 1.0969x over previous
//
#include <hip/hip_runtime.h>
#include <hip/hip_bf16.h>

typedef unsigned short u16;
typedef unsigned int   u32;

using bf16x8 = __attribute__((ext_vector_type(8))) short;
using f32x4  = __attribute__((ext_vector_type(4))) float;

// ---------- constants ----------
#define NB    32      // batch
#define CC    64      // in channels
#define WW_   4096    // input width
#define FF    128     // out channels
#define TAPS  9
#define NFFT  8192
#define KBINS 3597    // half_compressed
#define KB2   3616    // bins padded to 113*32 (PH table size)
#define N2    7194    // compress_fft_size
#define OW    4088    // out width
#define KP    7232    // padded 2*KBINS (mult of 64)
#define MP1   7424    // padded 2*KBINS cols for G1 (mult of 256)
#define SIG1  2048    // N*C
#define SIG2  4096    // N*F

__device__ __forceinline__ u16 f2bf(float f) {
    u32 u = __float_as_uint(f);
    return (u16)((u + 0x7FFFu + ((u >> 16) & 1u)) >> 16);
}
__device__ __forceinline__ float bf2f(u16 h) {
    return __uint_as_float(((u32)h) << 16);
}

// async global->LDS, 16B per lane; lds dest is wave-uniform base + lane*16
__device__ __forceinline__ void gload16(const void* g, void* l) {
    __builtin_amdgcn_global_load_lds(
        (const __attribute__((address_space(1))) void*)g,
        (__attribute__((address_space(3))) void*)l, 16, 0, 0);
}

// ---------- cast x to bf16 ----------
__global__ __launch_bounds__(256) void cast_x(const float* __restrict__ x,
                                              u16* __restrict__ xb, int n) {
    int stride = gridDim.x * blockDim.x;
    for (int i = blockIdx.x * blockDim.x + threadIdx.x; i < n; i += stride)
        xb[i] = f2bf(x[i]);
}

// ---------- merged prep: LUTs (blocks 0..31), PH (32..159), F2 (160..447) --
__global__ __launch_bounds__(256) void prep(float* __restrict__ L1,
                                            float2* __restrict__ L2,
                                            float2* __restrict__ PH,
                                            const float* __restrict__ filt,
                                            u16* __restrict__ F2) {
    int b = blockIdx.x;
    if (b < 32) {                      // L1[i]=cos(2pi i/8192); L2=(cos,sin)/7194
        int i = b * 256 + threadIdx.x;
        if (i < NFFT)
            L1[i] = cosf((float)i * (6.28318530717958647692f / (float)NFFT));
        if (i < N2) {
            float th = (float)i * (6.28318530717958647692f / (float)N2);
            float2 v;
            sincosf(th, &v.y, &v.x);
            L2[i] = v;
        }
    } else if (b < 160) {              // PH[w][bk]: (cos,sin) 2pi*bk*w/8192
        int idx = (b - 32) * 256 + threadIdx.x;
        if (idx < TAPS * KB2) {
            int w = idx / KB2, bk = idx % KB2;
            float2 v = {0.f, 0.f};
            if (bk < KBINS) {
                int r = (bk * w) & (NFFT - 1);
                float th = (float)r * (6.28318530717958647692f / (float)NFFT);
                sincosf(th, &v.y, &v.x);
            }
            PH[idx] = v;
        }
    } else {                           // F2[f][w*64+c] = bf16(filt[f][c][w])
        int idx = (b - 160) * 256 + threadIdx.x;
        if (idx < FF * 576) {
            int f = idx / 576, wc = idx % 576;
            int w = wc >> 6, c = wc & 63;
            F2[idx] = f2bf(filt[((size_t)f * CC + c) * TAPS + w]);
        }
    }
}

// ---------- Ttab[m][tau] via LUT; -sin(th) = cos(th + pi/2) = L1[r+2048] ---
__global__ __launch_bounds__(256) void gen_ttab(u16* __restrict__ T,
                                                const float* __restrict__ L1) {
    int m = blockIdx.x;              // 0..MP1-1
    int k = m >> 1;
    const int sh = (m & 1) ? 2048 : 0;
    const bool valid = (k < KBINS) && (m < 2 * KBINS);
    u32* row = (u32*)(T + (size_t)m * WW_);
    for (int p = threadIdx.x; p < WW_ / 2; p += 256) {
        u32 pack = 0;
        if (valid) {
            int r0 = (k * (2 * p) + sh) & (NFFT - 1);
            int r1 = (k * (2 * p + 1) + sh) & (NFFT - 1);
            pack = (u32)f2bf(L1[r0]) | ((u32)f2bf(L1[r1]) << 16);
        }
        row[p] = pack;
    }
}

// ---------- Dtab[t][k2] via LUT: pair (cos*sc, -sin*sc) for k=p ------------
__global__ __launch_bounds__(256) void gen_dtab(u16* __restrict__ D,
                                                const float2* __restrict__ L2) {
    int t = blockIdx.x;              // 0..4095
    u32* row = (u32*)(D + (size_t)t * KP);
    for (int p = threadIdx.x; p < KP / 2; p += 256) {
        u32 pack = 0;
        if (p < KBINS) {
            int r = (p * t) % N2;            // exact integer phase
            float2 cs = L2[r];
            float sc = (p == 0) ? (1.0f / (float)N2) : (2.0f / (float)N2);
            pack = (u32)f2bf(cs.x * sc) | ((u32)f2bf(-cs.y * sc) << 16);
        }
        row[p] = pack;
    }
}

// ============ 256x256 MFMA GEMM, 2-barrier/K-tile, 16x16x32 grain ==========
// (r7-exact structure — 32x32 grain reverted: its 32-row read spread costs a
// key-invariant 4 cyc/b128 bank penalty, r8/r9 measured.)
// Per K-tile t (cur=t&1): LOAD a0,b0,b1,a1 (24 ds_reads, issued up-front so
// the lgkm drain at BAR#1 is free); STAGE B(t+1)->nxt; q00; q01; lgkm(0);
// BAR#1; STAGE A(t+2)->cur (A region dead); q11; q10; vmcnt(4); BAR#2.
#define MFMA_Q(AS, BS, MH, NH)                                              \
    __builtin_amdgcn_s_setprio(1);                                          \
    _Pragma("unroll")                                                       \
    for (int kk = 0; kk < 2; kk++)                                          \
        _Pragma("unroll")                                                   \
        for (int m4 = 0; m4 < 4; m4++)                                      \
            _Pragma("unroll")                                               \
            for (int n2 = 0; n2 < 2; n2++)                                  \
                acc[(MH)*4 + m4][(NH)*2 + n2] =                             \
                    __builtin_amdgcn_mfma_f32_16x16x32_bf16(                \
                        AS[m4][kk], BS[n2][kk],                             \
                        acc[(MH)*4 + m4][(NH)*2 + n2], 0, 0, 0);            \
    __builtin_amdgcn_s_setprio(0);

#define LOAD_A(AS, MH, BUF)                                                 \
    _Pragma("unroll")                                                       \
    for (int m4 = 0; m4 < 4; m4++)                                          \
        _Pragma("unroll")                                                   \
        for (int kk = 0; kk < 2; kk++) {                                    \
            int row_ = wr * 128 + (MH)*64 + m4 * 16 + fr;                   \
            AS[m4][kk] = *(const bf16x8*)(smem + (BUF)*32768 +              \
                          row_ * 128 + ((kk * 64 + hk) ^ askew));           \
        }

#define LOAD_B(BS, NH, BUF)                                                 \
    _Pragma("unroll")                                                       \
    for (int n2 = 0; n2 < 2; n2++)                                          \
        _Pragma("unroll")                                                   \
        for (int kk = 0; kk < 2; kk++) {                                    \
            int row_ = wc * 64 + (NH)*32 + n2 * 16 + fr;                    \
            BS[n2][kk] = *(const bf16x8*)(smem + 65536 + (BUF)*32768 +      \
                          row_ * 128 + ((kk * 64 + hk) ^ askew));           \
        }

#define STAGE(Q, R, BUF)                                                    \
    {                                                                       \
        const u16* g_ = ((R) < 2) ? gA : gB;                                \
        size_t ro_ = (size_t)((R)&1) * 128 * K;                             \
        int lb_ = (((R) < 2) ? 0 : 65536) + (BUF)*32768 +                   \
                  (((R)&1) * 128 + wid * 16) * 128;                         \
        gload16(g_ + ro_ + (Q)*64, smem + lb_);                             \
        gload16(g_ + ro_ + (size_t)8 * K + (Q)*64, smem + lb_ + 1024);      \
    }

#define BAR() __builtin_amdgcn_s_barrier()

template <int MODE>
__global__ __launch_bounds__(512, 1) void gemm256(const u16* __restrict__ A,
                                                  const u16* __restrict__ B,
                                                  int K, int gridN,
                                                  void* __restrict__ Out,
                                                  int ldo,
                                                  const float* __restrict__ bias) {
    extern __shared__ char smem[];   // [A b0|A b1|B b0|B b1] x 32KB
    const int tid = threadIdx.x;
    const int lane = tid & 63, wid = tid >> 6;
    const int wr = wid >> 2, wc = wid & 3;
    const int fr = lane & 15;
    const int hk = (lane >> 4) << 4;
    const int askew = (fr & 7) << 4;

    const int nwg = (int)gridDim.x, cpx = nwg >> 3;
    const int bid = (int)blockIdx.x;
    const int wg = (bid & 7) * cpx + (bid >> 3);
    const int tm = wg / gridN, tn = wg % gridN;
    const int NT = K >> 6;

    f32x4 acc[8][4];
#pragma unroll
    for (int i = 0; i < 8; i++)
#pragma unroll
        for (int j = 0; j < 4; j++) acc[i][j] = (f32x4){0.f, 0.f, 0.f, 0.f};

    const int srow = lane >> 3;
    const int scol = ((lane & 7) ^ srow) * 8;
    const u16* gA = A + (size_t)(tm * 256 + wid * 16 + srow) * K + scol;
    const u16* gB = B + (size_t)(tn * 256 + wid * 16 + srow) * K + scol;

    // prologue: full tile0 -> buf0, A(1) -> buf1; leaves A(1) in flight
    STAGE(0, 0, 0) STAGE(0, 1, 0) STAGE(0, 2, 0) STAGE(0, 3, 0)
    STAGE(1, 0, 1) STAGE(1, 1, 1)
    asm volatile("s_waitcnt vmcnt(4)" ::: "memory");
    BAR();

    bf16x8 a0[4][2], a1[4][2], b0[2][2], b1[2][2];
    for (int t = 0; t < NT; ++t) {
        const int cur = t & 1, nxt = cur ^ 1;
        LOAD_A(a0, 0, cur)
        LOAD_B(b0, 0, cur)
        LOAD_B(b1, 1, cur)
        LOAD_A(a1, 1, cur)           // issued up-front: lgkm(0) below is free
        if (t + 1 < NT) { STAGE(t + 1, 2, nxt) STAGE(t + 1, 3, nxt) }
        MFMA_Q(a0, b0, 0, 0)
        MFMA_Q(a0, b1, 0, 1)
        asm volatile("s_waitcnt lgkmcnt(0)" ::: "memory");  // cur-A reads done
        __builtin_amdgcn_sched_barrier(0);
        BAR();                       // #1: cur-A region now dead block-wide
        if (t + 2 < NT) { STAGE(t + 2, 0, cur) STAGE(t + 2, 1, cur) }
        MFMA_Q(a1, b1, 1, 1)
        MFMA_Q(a1, b0, 1, 0)
        if (t + 2 < NT) {
            asm volatile("s_waitcnt vmcnt(4)" ::: "memory");  // A(t+1),B(t+1) in
        } else if (t + 1 < NT) {
            asm volatile("s_waitcnt vmcnt(0)" ::: "memory");  // drain for last
        }
        BAR();                       // #2: publish nxt
    }

    // epilogue: C/D frag layout col=lane&15, row=(lane>>4)*4+j  [m89]
#pragma unroll
    for (int m = 0; m < 8; m++) {
#pragma unroll
        for (int n = 0; n < 4; n++) {
            int col  = tn * 256 + wc * 64 + n * 16 + fr;
            int row0 = tm * 256 + wr * 128 + m * 16 + ((lane >> 4) << 2);
#pragma unroll
            for (int j = 0; j < 4; j++) {
                int grow = row0 + j;
                if (MODE == 0) {
                    ((u16*)Out)[(size_t)grow * ldo + col] = f2bf(acc[m][n][j]);
                } else {
                    if (col < OW) {
                        ((float*)Out)[(size_t)grow * OW + col] =
                            acc[m][n][j] + bias[grow & 127];
                    }
                }
            }
        }
    }
}

// ============ step_c2: spectral contraction as one MFMA GEMM over (c,w) ====
// spec[n,f,k] = sum_{c,w} filt[f,c,w] * (X[n,c,k] * e^{i*2pi*k*w/8192})
#define ZBUILD(T, BUF)                                                      \
    {                                                                       \
        float2 ph = lph[(T) * 32 + zk];                                     \
        bf16x8 zr, zi;                                                      \
        _Pragma("unroll")                                                   \
        for (int j = 0; j < 8; j++) {                                       \
            int c_ = zcb * 8 + j;                                           \
            u32 xv = lxu[c_ * 32 +                                          \
                         (((zk >> 2) ^ j ^ zcb) << 2) + (zk & 3)];          \
            float xr = bf2f((u16)(xv & 0xffff));                            \
            float xi = bf2f((u16)(xv >> 16));                               \
            zr[j] = (short)f2bf(xr * ph.x - xi * ph.y);                     \
            zi[j] = (short)f2bf(xi * ph.x + xr * ph.y);                     \
        }                                                                   \
        int rR = 2 * zk, rI = 2 * zk + 1;                                   \
        *(bf16x8*)(lzc + (BUF)*8192 + rR * 128 + ((zcb ^ (rR & 7)) << 4)) = zr; \
        *(bf16x8*)(lzc + (BUF)*8192 + rI * 128 + ((zcb ^ (rI & 7)) << 4)) = zi; \
    }

#define STAGE_A2(T, BUF)                                                    \
    _Pragma("unroll")                                                       \
    for (int j = 0; j < 4; j++) {                                           \
        gload16(F2 + (size_t)(wid * 32 + j * 8 + (lane >> 3)) * 576 +       \
                    (T) * 64 + (((lane & 7) ^ (lane >> 3)) * 8),            \
                lac + (BUF)*16384 + (wid * 32 + j * 8) * 128);              \
    }

__global__ __launch_bounds__(256, 2) void step_c2(const u16* __restrict__ XF_,
                                                  const u16* __restrict__ F2,
                                                  const float2* __restrict__ PH,
                                                  u16* __restrict__ S) {
    __shared__ u16 la[2 * 128 * 64];    // 32 KB  A double-buffer
    __shared__ u16 lz[2 * 64 * 64];     // 16 KB  Z double-buffer
    __shared__ u32 lx[64 * 32];         // 8 KB   X tile (packed complex, swz)
    __shared__ float2 lph[TAPS * 32];   // 2.25 KB
    const int tid = threadIdx.x;
    const int lane = tid & 63, wid = tid >> 6;
    const int kt = blockIdx.x, n = blockIdx.y;
    const int fr = lane & 15;
    const int hk = (lane >> 4) << 4;
    const int askew = (fr & 7) << 4;
    char* lac = (char*)la;
    char* lzc = (char*)lz;
    char* lxc = (char*)lx;
    const u32* lxu = lx;
    const int zk = tid >> 3;            // 0..31 local bin
    const int zcb = tid & 7;            // c-block of 8

    // stage X tile: rows c = wid*16+j*8+(lane>>3), 16B col16 ^= (c&7)^(c>>3)
#pragma unroll
    for (int j = 0; j < 2; j++) {
        int c_ = wid * 16 + j * 8 + (lane >> 3);
        gload16(XF_ + (size_t)(n * 64 + c_) * MP1 + kt * 64 +
                    (((lane & 7) ^ (lane >> 3) ^ (wid * 2 + j)) * 8),
                lxc + (wid * 16 + j * 8) * 128);
    }
    // lph: 288 entries > 256 threads -> grid-stride
    for (int i = tid; i < TAPS * 32; i += 256) {
        int w_ = i >> 5, b_ = i & 31;
        lph[i] = PH[w_ * KB2 + kt * 32 + b_];
    }
    __syncthreads();

    f32x4 acc[2][4];
#pragma unroll
    for (int i = 0; i < 2; i++)
#pragma unroll
        for (int j = 0; j < 4; j++) acc[i][j] = (f32x4){0.f, 0.f, 0.f, 0.f};

    ZBUILD(0, 0)
    STAGE_A2(0, 0)
    __syncthreads();

    bf16x8 af[2][2], bfr[4][2];
    for (int t = 0; t < TAPS; ++t) {
        const int cur = t & 1, nxt = cur ^ 1;
#pragma unroll
        for (int m2 = 0; m2 < 2; m2++)
#pragma unroll
            for (int kk = 0; kk < 2; kk++) {
                int row_ = wid * 32 + m2 * 16 + fr;
                af[m2][kk] = *(const bf16x8*)(lac + cur * 16384 + row_ * 128 +
                                              ((kk * 64 + hk) ^ askew));
            }
#pragma unroll
        for (int n4 = 0; n4 < 4; n4++)
#pragma unroll
            for (int kk = 0; kk < 2; kk++) {
                int row_ = n4 * 16 + fr;
                bfr[n4][kk] = *(const bf16x8*)(lzc + cur * 8192 + row_ * 128 +
                                               ((kk * 64 + hk) ^ askew));
            }
        if (t + 1 < TAPS) {
            ZBUILD(t + 1, nxt)
            STAGE_A2(t + 1, nxt)
        }
        __builtin_amdgcn_s_setprio(1);
#pragma unroll
        for (int kk = 0; kk < 2; kk++)
#pragma unroll
            for (int m2 = 0; m2 < 2; m2++)
#pragma unroll
                for (int n4 = 0; n4 < 4; n4++)
                    acc[m2][n4] = __builtin_amdgcn_mfma_f32_16x16x32_bf16(
                        af[m2][kk], bfr[n4][kk], acc[m2][n4], 0, 0, 0);
        __builtin_amdgcn_s_setprio(0);
        __syncthreads();
    }

    // epilogue: S[n*128+f][kt*64+col], C/D layout col=lane&15,row=(lane>>4)*4+j
#pragma unroll
    for (int m2 = 0; m2 < 2; m2++) {
#pragma unroll
        for (int n4 = 0; n4 < 4; n4++) {
            int colk = kt * 64 + n4 * 16 + fr;
            int f0 = wid * 32 + m2 * 16 + ((lane >> 4) << 2);
#pragma unroll
            for (int j = 0; j < 4; j++) {
                int sig2 = n * 128 + f0 + j;
                S[(size_t)sig2 * KP + colk] = f2bf(acc[m2][n4][j]);
            }
        }
    }
}

// ---------- launch ----------
extern "C" void kernel_launch(void* const* d_in, const int* in_sizes, int n_in,
                              void* d_out, int out_size, void* d_ws, size_t ws_size,
                              hipStream_t stream) {
    (void)in_sizes; (void)n_in; (void)out_size; (void)ws_size;
    const float* x    = (const float*)d_in[0];
    const float* filt = (const float*)d_in[1];
    const float* bias = (const float*)d_in[2];

    char* ws = (char*)d_ws;
    u16* TT = (u16*)(ws);                  // 60,817,408 B (Ttab, then Dtab)
    u16* XF = (u16*)(ws + 60817408);       // 2048 x 7424 bf16 = 30,408,704
    u16* XB = (u16*)(ws + 91226112);       // 2048 x 4096 bf16 = 16,777,216
    u16* S  = (u16*)(ws + 108003328);      // 4096 x 7232 bf16 = 59,244,544
    u16* F2 = (u16*)(ws + 167247872);      // 128 x 576 bf16   = 147,456
    float2* PH = (float2*)(ws + 167395328); // 9 x 3616 float2 = 260,352
    float*  L1 = (float*)(ws + 167655680);  // 8192 f32        = 32,768
    float2* L2 = (float2*)(ws + 167688448); // 7194 float2     = 57,552
    // total: 167,746,000 B

    hipFuncSetAttribute(reinterpret_cast<const void*>(gemm256<0>),
                        hipFuncAttributeMaxDynamicSharedMemorySize, 131072);
    hipFuncSetAttribute(reinterpret_cast<const void*>(gemm256<1>),
                        hipFuncAttributeMaxDynamicSharedMemorySize, 131072);

    cast_x<<<4096, 256, 0, stream>>>(x, XB, NB * CC * WW_);
    prep<<<448, 256, 0, stream>>>(L1, L2, PH, filt, F2);
    gen_ttab<<<MP1, 256, 0, stream>>>(TT, L1);
    gemm256<0><<<8 * (MP1 / 256), 512, 131072, stream>>>(
        XB, TT, WW_, MP1 / 256, XF, MP1, nullptr);
    gen_dtab<<<SIG2, 256, 0, stream>>>(TT, L2);   // overwrites Ttab (dead)
    step_c2<<<dim3(KP / 64, NB), 256, 0, stream>>>(XF, F2, PH, S);
    gemm256<1><<<16 * 16, 512, 131072, stream>>>(
        S, TT, KP, 16, d_out, OW, bias);
}

// Round 11
// 402.344 us; speedup vs baseline: 1.2691x; 1.1488x over previous
//
#include <hip/hip_runtime.h>
#include <hip/hip_bf16.h>

typedef unsigned short u16;
typedef unsigned int   u32;

using bf16x8 = __attribute__((ext_vector_type(8))) short;
using f32x4  = __attribute__((ext_vector_type(4))) float;

// ---------- constants ----------
#define NB    32      // batch
#define CC    64      // in channels
#define WW_   4096    // input width
#define FF    128     // out channels
#define TAPS  9
#define NFFT  8192
#define KBINS 3597    // half_compressed
#define KB2   3616    // bins padded to 113*32 (PH table size)
#define N2    7194    // compress_fft_size
#define OW    4088    // out width
#define KP    7232    // padded 2*KBINS (mult of 64)
#define MP1   7424    // padded 2*KBINS cols for G1 (mult of 256)
#define SIG1  2048    // N*C
#define SIG2  4096    // N*F

__device__ __forceinline__ u16 f2bf(float f) {
    u32 u = __float_as_uint(f);
    return (u16)((u + 0x7FFFu + ((u >> 16) & 1u)) >> 16);
}
__device__ __forceinline__ float bf2f(u16 h) {
    return __uint_as_float(((u32)h) << 16);
}
// HW trig, input in REVOLUTIONS (ISA: D=sin(S0*2pi)); arg in [0,1) -> no
// range reduction needed. bf16 tables need only 8 mantissa bits.
__device__ __forceinline__ float vsin(float x) {
    float r; asm("v_sin_f32 %0, %1" : "=v"(r) : "v"(x)); return r;
}
__device__ __forceinline__ float vcos(float x) {
    float r; asm("v_cos_f32 %0, %1" : "=v"(r) : "v"(x)); return r;
}

// async global->LDS, 16B per lane; lds dest is wave-uniform base + lane*16
__device__ __forceinline__ void gload16(const void* g, void* l) {
    __builtin_amdgcn_global_load_lds(
        (const __attribute__((address_space(1))) void*)g,
        (__attribute__((address_space(3))) void*)l, 16, 0, 0);
}

// ---------- cast x to bf16 ----------
__global__ __launch_bounds__(256) void cast_x(const float* __restrict__ x,
                                              u16* __restrict__ xb, int n) {
    int stride = gridDim.x * blockDim.x;
    for (int i = blockIdx.x * blockDim.x + threadIdx.x; i < n; i += stride)
        xb[i] = f2bf(x[i]);
}

// ---------- merged prep: PH (blocks 0..127), F2 (128..415) ----------
__global__ __launch_bounds__(256) void prep(float2* __restrict__ PH,
                                            const float* __restrict__ filt,
                                            u16* __restrict__ F2) {
    int b = blockIdx.x;
    if (b < 128) {                     // PH[w][bk]: (cos,sin) 2pi*bk*w/8192
        int idx = b * 256 + threadIdx.x;
        if (idx < TAPS * KB2) {
            int w = idx / KB2, bk = idx % KB2;
            float2 v = {0.f, 0.f};
            if (bk < KBINS) {
                int r = (bk * w) & (NFFT - 1);
                float th = (float)r * (6.28318530717958647692f / (float)NFFT);
                sincosf(th, &v.y, &v.x);
            }
            PH[idx] = v;
        }
    } else {                           // F2[f][w*64+c] = bf16(filt[f][c][w])
        int idx = (b - 128) * 256 + threadIdx.x;
        if (idx < FF * 576) {
            int f = idx / 576, wc = idx % 576;
            int w = wc >> 6, c = wc & 63;
            F2[idx] = f2bf(filt[((size_t)f * CC + c) * TAPS + w]);
        }
    }
}

// ---------- Ttab[m][tau], m=2k(+1): cos / -sin of 2*pi*k*tau/8192 ----------
__global__ __launch_bounds__(256) void gen_ttab(u16* __restrict__ T) {
    int m = blockIdx.x;              // 0..MP1-1
    int k = m >> 1;
    const bool valid = (k < KBINS) && (m < 2 * KBINS);
    const bool neg = (m & 1);
    u32* row = (u32*)(T + (size_t)m * WW_);
    for (int p = threadIdx.x; p < WW_ / 2; p += 256) {
        u32 pack = 0;
        if (valid) {
            int r0 = (k * (2 * p)) & (NFFT - 1);       // exact integer phase
            int r1 = (r0 + k) & (NFFT - 1);
            float v0, v1;
            if (neg) {
                v0 = -vsin((float)r0 * (1.0f / NFFT));
                v1 = -vsin((float)r1 * (1.0f / NFFT));
            } else {
                v0 = vcos((float)r0 * (1.0f / NFFT));
                v1 = vcos((float)r1 * (1.0f / NFFT));
            }
            pack = (u32)f2bf(v0) | ((u32)f2bf(v1) << 16);
        }
        row[p] = pack;
    }
}

// ---------- Dtab[t][k2]: pair (cos*sc, -sin*sc) for bin p ------------------
__global__ __launch_bounds__(256) void gen_dtab(u16* __restrict__ D) {
    int t = blockIdx.x;              // 0..4095
    u32* row = (u32*)(D + (size_t)t * KP);
    for (int p = threadIdx.x; p < KP / 2; p += 256) {
        u32 pack = 0;
        if (p < KBINS) {
            int r = (p * t) % N2;            // exact integer phase
            float rev = (float)r * (1.0f / N2);
            float sc = (p == 0) ? (1.0f / (float)N2) : (2.0f / (float)N2);
            pack = (u32)f2bf(vcos(rev) * sc) |
                   ((u32)f2bf(-vsin(rev) * sc) << 16);
        }
        row[p] = pack;
    }
}

// ============ 256x256 MFMA GEMM, 2-barrier/K-tile, 16x16x32 grain ==========
// r7-exact schedule (known-good 202us G2): per K-tile t (cur=t&1):
//   LOAD a0,b0,b1 (cur); STAGE B(t+1)->nxt; q00; LOAD a1 (under q00 shadow);
//   q01; lgkm(0); BAR#1; STAGE A(t+2)->cur (A dead); q11; q10; vmcnt(4);
//   BAR#2.  Prologue: tile0+A(1); tails drain.
#define MFMA_Q(AS, BS, MH, NH)                                              \
    __builtin_amdgcn_s_setprio(1);                                          \
    _Pragma("unroll")                                                       \
    for (int kk = 0; kk < 2; kk++)                                          \
        _Pragma("unroll")                                                   \
        for (int m4 = 0; m4 < 4; m4++)                                      \
            _Pragma("unroll")                                               \
            for (int n2 = 0; n2 < 2; n2++)                                  \
                acc[(MH)*4 + m4][(NH)*2 + n2] =                             \
                    __builtin_amdgcn_mfma_f32_16x16x32_bf16(                \
                        AS[m4][kk], BS[n2][kk],                             \
                        acc[(MH)*4 + m4][(NH)*2 + n2], 0, 0, 0);            \
    __builtin_amdgcn_s_setprio(0);

#define LOAD_A(AS, MH, BUF)                                                 \
    _Pragma("unroll")                                                       \
    for (int m4 = 0; m4 < 4; m4++)                                          \
        _Pragma("unroll")                                                   \
        for (int kk = 0; kk < 2; kk++) {                                    \
            int row_ = wr * 128 + (MH)*64 + m4 * 16 + fr;                   \
            AS[m4][kk] = *(const bf16x8*)(smem + (BUF)*32768 +              \
                          row_ * 128 + ((kk * 64 + hk) ^ askew));           \
        }

#define LOAD_B(BS, NH, BUF)                                                 \
    _Pragma("unroll")                                                       \
    for (int n2 = 0; n2 < 2; n2++)                                          \
        _Pragma("unroll")                                                   \
        for (int kk = 0; kk < 2; kk++) {                                    \
            int row_ = wc * 64 + (NH)*32 + n2 * 16 + fr;                    \
            BS[n2][kk] = *(const bf16x8*)(smem + 65536 + (BUF)*32768 +      \
                          row_ * 128 + ((kk * 64 + hk) ^ askew));           \
        }

#define STAGE(Q, R, BUF)                                                    \
    {                                                                       \
        const u16* g_ = ((R) < 2) ? gA : gB;                                \
        size_t ro_ = (size_t)((R)&1) * 128 * K;                             \
        int lb_ = (((R) < 2) ? 0 : 65536) + (BUF)*32768 +                   \
                  (((R)&1) * 128 + wid * 16) * 128;                         \
        gload16(g_ + ro_ + (Q)*64, smem + lb_);                             \
        gload16(g_ + ro_ + (size_t)8 * K + (Q)*64, smem + lb_ + 1024);      \
    }

#define BAR() __builtin_amdgcn_s_barrier()

template <int MODE>
__global__ __launch_bounds__(512, 1) void gemm256(const u16* __restrict__ A,
                                                  const u16* __restrict__ B,
                                                  int K, int gridN,
                                                  void* __restrict__ Out,
                                                  int ldo,
                                                  const float* __restrict__ bias) {
    extern __shared__ char smem[];   // [A b0|A b1|B b0|B b1] x 32KB
    const int tid = threadIdx.x;
    const int lane = tid & 63, wid = tid >> 6;
    const int wr = wid >> 2, wc = wid & 3;
    const int fr = lane & 15;
    const int hk = (lane >> 4) << 4;
    const int askew = (fr & 7) << 4;

    const int nwg = (int)gridDim.x, cpx = nwg >> 3;
    const int bid = (int)blockIdx.x;
    const int wg = (bid & 7) * cpx + (bid >> 3);
    const int tm = wg / gridN, tn = wg % gridN;
    const int NT = K >> 6;

    f32x4 acc[8][4];
#pragma unroll
    for (int i = 0; i < 8; i++)
#pragma unroll
        for (int j = 0; j < 4; j++) acc[i][j] = (f32x4){0.f, 0.f, 0.f, 0.f};

    const int srow = lane >> 3;
    const int scol = ((lane & 7) ^ srow) * 8;
    const u16* gA = A + (size_t)(tm * 256 + wid * 16 + srow) * K + scol;
    const u16* gB = B + (size_t)(tn * 256 + wid * 16 + srow) * K + scol;

    // prologue: full tile0 -> buf0, A(1) -> buf1; leaves A(1) in flight
    STAGE(0, 0, 0) STAGE(0, 1, 0) STAGE(0, 2, 0) STAGE(0, 3, 0)
    STAGE(1, 0, 1) STAGE(1, 1, 1)
    asm volatile("s_waitcnt vmcnt(4)" ::: "memory");
    BAR();

    bf16x8 a0[4][2], a1[4][2], b0[2][2], b1[2][2];
    for (int t = 0; t < NT; ++t) {
        const int cur = t & 1, nxt = cur ^ 1;
        LOAD_A(a0, 0, cur)
        LOAD_B(b0, 0, cur)
        LOAD_B(b1, 1, cur)
        if (t + 1 < NT) { STAGE(t + 1, 2, nxt) STAGE(t + 1, 3, nxt) }
        MFMA_Q(a0, b0, 0, 0)
        LOAD_A(a1, 1, cur)          // issued under q01's MFMA shadow
        MFMA_Q(a0, b1, 0, 1)
        asm volatile("s_waitcnt lgkmcnt(0)" ::: "memory");  // cur-A reads done
        __builtin_amdgcn_sched_barrier(0);
        BAR();                       // #1: cur-A region now dead block-wide
        if (t + 2 < NT) { STAGE(t + 2, 0, cur) STAGE(t + 2, 1, cur) }
        MFMA_Q(a1, b1, 1, 1)
        MFMA_Q(a1, b0, 1, 0)
        if (t + 2 < NT) {
            asm volatile("s_waitcnt vmcnt(4)" ::: "memory");  // A(t+1),B(t+1) in
        } else if (t + 1 < NT) {
            asm volatile("s_waitcnt vmcnt(0)" ::: "memory");  // drain for last
        }
        BAR();                       // #2: publish nxt
    }

    // epilogue: C/D frag layout col=lane&15, row=(lane>>4)*4+j  [m89]
#pragma unroll
    for (int m = 0; m < 8; m++) {
#pragma unroll
        for (int n = 0; n < 4; n++) {
            int col  = tn * 256 + wc * 64 + n * 16 + fr;
            int row0 = tm * 256 + wr * 128 + m * 16 + ((lane >> 4) << 2);
#pragma unroll
            for (int j = 0; j < 4; j++) {
                int grow = row0 + j;
                if (MODE == 0) {
                    ((u16*)Out)[(size_t)grow * ldo + col] = f2bf(acc[m][n][j]);
                } else {
                    if (col < OW) {
                        ((float*)Out)[(size_t)grow * OW + col] =
                            acc[m][n][j] + bias[grow & 127];
                    }
                }
            }
        }
    }
}

// ============ step_c2: spectral contraction as one MFMA GEMM over (c,w) ====
// spec[n,f,k] = sum_{c,w} filt[f,c,w] * (X[n,c,k] * e^{i*2pi*k*w/8192})
#define ZBUILD(T, BUF)                                                      \
    {                                                                       \
        float2 ph = lph[(T) * 32 + zk];                                     \
        bf16x8 zr, zi;                                                      \
        _Pragma("unroll")                                                   \
        for (int j = 0; j < 8; j++) {                                       \
            int c_ = zcb * 8 + j;                                           \
            u32 xv = lxu[c_ * 32 +                                          \
                         (((zk >> 2) ^ j ^ zcb) << 2) + (zk & 3)];          \
            float xr = bf2f((u16)(xv & 0xffff));                            \
            float xi = bf2f((u16)(xv >> 16));                               \
            zr[j] = (short)f2bf(xr * ph.x - xi * ph.y);                     \
            zi[j] = (short)f2bf(xi * ph.x + xr * ph.y);                     \
        }                                                                   \
        int rR = 2 * zk, rI = 2 * zk + 1;                                   \
        *(bf16x8*)(lzc + (BUF)*8192 + rR * 128 + ((zcb ^ (rR & 7)) << 4)) = zr; \
        *(bf16x8*)(lzc + (BUF)*8192 + rI * 128 + ((zcb ^ (rI & 7)) << 4)) = zi; \
    }

#define STAGE_A2(T, BUF)                                                    \
    _Pragma("unroll")                                                       \
    for (int j = 0; j < 4; j++) {                                           \
        gload16(F2 + (size_t)(wid * 32 + j * 8 + (lane >> 3)) * 576 +       \
                    (T) * 64 + (((lane & 7) ^ (lane >> 3)) * 8),            \
                lac + (BUF)*16384 + (wid * 32 + j * 8) * 128);              \
    }

__global__ __launch_bounds__(256, 2) void step_c2(const u16* __restrict__ XF_,
                                                  const u16* __restrict__ F2,
                                                  const float2* __restrict__ PH,
                                                  u16* __restrict__ S) {
    __shared__ u16 la[2 * 128 * 64];    // 32 KB  A double-buffer
    __shared__ u16 lz[2 * 64 * 64];     // 16 KB  Z double-buffer
    __shared__ u32 lx[64 * 32];         // 8 KB   X tile (packed complex, swz)
    __shared__ float2 lph[TAPS * 32];   // 2.25 KB
    const int tid = threadIdx.x;
    const int lane = tid & 63, wid = tid >> 6;
    const int kt = blockIdx.x, n = blockIdx.y;
    const int fr = lane & 15;
    const int hk = (lane >> 4) << 4;
    const int askew = (fr & 7) << 4;
    char* lac = (char*)la;
    char* lzc = (char*)lz;
    char* lxc = (char*)lx;
    const u32* lxu = lx;
    const int zk = tid >> 3;            // 0..31 local bin
    const int zcb = tid & 7;            // c-block of 8

    // stage X tile: rows c = wid*16+j*8+(lane>>3), 16B col16 ^= (c&7)^(c>>3)
#pragma unroll
    for (int j = 0; j < 2; j++) {
        int c_ = wid * 16 + j * 8 + (lane >> 3);
        gload16(XF_ + (size_t)(n * 64 + c_) * MP1 + kt * 64 +
                    (((lane & 7) ^ (lane >> 3) ^ (wid * 2 + j)) * 8),
                lxc + (wid * 16 + j * 8) * 128);
    }
    // lph: 288 entries > 256 threads -> grid-stride
    for (int i = tid; i < TAPS * 32; i += 256) {
        int w_ = i >> 5, b_ = i & 31;
        lph[i] = PH[w_ * KB2 + kt * 32 + b_];
    }
    __syncthreads();

    f32x4 acc[2][4];
#pragma unroll
    for (int i = 0; i < 2; i++)
#pragma unroll
        for (int j = 0; j < 4; j++) acc[i][j] = (f32x4){0.f, 0.f, 0.f, 0.f};

    ZBUILD(0, 0)
    STAGE_A2(0, 0)
    __syncthreads();

    bf16x8 af[2][2], bfr[4][2];
    for (int t = 0; t < TAPS; ++t) {
        const int cur = t & 1, nxt = cur ^ 1;
#pragma unroll
        for (int m2 = 0; m2 < 2; m2++)
#pragma unroll
            for (int kk = 0; kk < 2; kk++) {
                int row_ = wid * 32 + m2 * 16 + fr;
                af[m2][kk] = *(const bf16x8*)(lac + cur * 16384 + row_ * 128 +
                                              ((kk * 64 + hk) ^ askew));
            }
#pragma unroll
        for (int n4 = 0; n4 < 4; n4++)
#pragma unroll
            for (int kk = 0; kk < 2; kk++) {
                int row_ = n4 * 16 + fr;
                bfr[n4][kk] = *(const bf16x8*)(lzc + cur * 8192 + row_ * 128 +
                                               ((kk * 64 + hk) ^ askew));
            }
        if (t + 1 < TAPS) {
            ZBUILD(t + 1, nxt)
            STAGE_A2(t + 1, nxt)
        }
        __builtin_amdgcn_s_setprio(1);
#pragma unroll
        for (int kk = 0; kk < 2; kk++)
#pragma unroll
            for (int m2 = 0; m2 < 2; m2++)
#pragma unroll
                for (int n4 = 0; n4 < 4; n4++)
                    acc[m2][n4] = __builtin_amdgcn_mfma_f32_16x16x32_bf16(
                        af[m2][kk], bfr[n4][kk], acc[m2][n4], 0, 0, 0);
        __builtin_amdgcn_s_setprio(0);
        __syncthreads();
    }

    // epilogue: S[n*128+f][kt*64+col], C/D layout col=lane&15,row=(lane>>4)*4+j
#pragma unroll
    for (int m2 = 0; m2 < 2; m2++) {
#pragma unroll
        for (int n4 = 0; n4 < 4; n4++) {
            int colk = kt * 64 + n4 * 16 + fr;
            int f0 = wid * 32 + m2 * 16 + ((lane >> 4) << 2);
#pragma unroll
            for (int j = 0; j < 4; j++) {
                int sig2 = n * 128 + f0 + j;
                S[(size_t)sig2 * KP + colk] = f2bf(acc[m2][n4][j]);
            }
        }
    }
}

// ---------- launch ----------
extern "C" void kernel_launch(void* const* d_in, const int* in_sizes, int n_in,
                              void* d_out, int out_size, void* d_ws, size_t ws_size,
                              hipStream_t stream) {
    (void)in_sizes; (void)n_in; (void)out_size; (void)ws_size;
    const float* x    = (const float*)d_in[0];
    const float* filt = (const float*)d_in[1];
    const float* bias = (const float*)d_in[2];

    char* ws = (char*)d_ws;
    u16* TT = (u16*)(ws);                  // 60,817,408 B (Ttab, then Dtab)
    u16* XF = (u16*)(ws + 60817408);       // 2048 x 7424 bf16 = 30,408,704
    u16* XB = (u16*)(ws + 91226112);       // 2048 x 4096 bf16 = 16,777,216
    u16* S  = (u16*)(ws + 108003328);      // 4096 x 7232 bf16 = 59,244,544
    u16* F2 = (u16*)(ws + 167247872);      // 128 x 576 bf16   = 147,456
    float2* PH = (float2*)(ws + 167395328); // 9 x 3616 float2 = 260,352
    // total: 167,655,680 B

    hipFuncSetAttribute(reinterpret_cast<const void*>(gemm256<0>),
                        hipFuncAttributeMaxDynamicSharedMemorySize, 131072);
    hipFuncSetAttribute(reinterpret_cast<const void*>(gemm256<1>),
                        hipFuncAttributeMaxDynamicSharedMemorySize, 131072);

    cast_x<<<4096, 256, 0, stream>>>(x, XB, NB * CC * WW_);
    prep<<<416, 256, 0, stream>>>(PH, filt, F2);
    gen_ttab<<<MP1, 256, 0, stream>>>(TT);
    gemm256<0><<<8 * (MP1 / 256), 512, 131072, stream>>>(
        XB, TT, WW_, MP1 / 256, XF, MP1, nullptr);
    gen_dtab<<<SIG2, 256, 0, stream>>>(TT);   // overwrites Ttab (dead)
    step_c2<<<dim3(KP / 64, NB), 256, 0, stream>>>(XF, F2, PH, S);
    gemm256<1><<<16 * 16, 512, 131072, stream>>>(
        S, TT, KP, 16, d_out, OW, bias);
}

// Round 12
// 201.812 us; speedup vs baseline: 2.5301x; 1.9937x over previous
//
#include <hip/hip_runtime.h>
#include <hip/hip_bf16.h>

typedef unsigned short u16;
typedef unsigned int   u32;

using bf16x8 = __attribute__((ext_vector_type(8))) short;
using f32x4  = __attribute__((ext_vector_type(4))) float;

// ---------- constants ----------
#define NB    32      // batch
#define CC    64      // in channels
#define WW_   4096    // input width
#define FF    128     // out channels
#define TAPS  9
#define KBINS 3597    // half_compressed
#define N2    7194    // compress_fft_size
#define OW    4088    // out width
#define SIG2  4096    // N*F
#define JMAX  4104    // conv support: tau in [-8,4095], j = tau+8
#define KD    4160    // padded conv length (mult of 64)
#define XTROWS 4352   // 64 zero + 4096 data + 192 zero
#define PBIG  58933248LL   // 8192*7194

__device__ __forceinline__ u16 f2bf(float f) {
    u32 u = __float_as_uint(f);
    return (u16)((u + 0x7FFFu + ((u >> 16) & 1u)) >> 16);
}
// HW trig, input in REVOLUTIONS (ISA: D=sin(S0*2pi)), arg kept in [0,1)
__device__ __forceinline__ float vsin(float x) {
    float r; asm("v_sin_f32 %0, %1" : "=v"(r) : "v"(x)); return r;
}

// async global->LDS, 16B per lane; lds dest is wave-uniform base + lane*16
__device__ __forceinline__ void gload16(const void* g, void* l) {
    __builtin_amdgcn_global_load_lds(
        (const __attribute__((address_space(1))) void*)g,
        (__attribute__((address_space(3))) void*)l, 16, 0, 0);
}

// ---------- cast + transpose x into XT[n][R][c-swizzled] ----------
// XT row R = x col (R-64); mem pos pb*8+ci holds channel (pb^(R&7))*8+ci.
__global__ __launch_bounds__(256) void cast_xt(const float* __restrict__ x,
                                               u16* __restrict__ XT) {
    __shared__ u16 tl[64][72];
    const int tid = threadIdx.x;
    const int it = blockIdx.x, n = blockIdx.y;
    const int i0 = it * 64;
    {   // read x[n][c][i0+io .. +15] coalesced, c = tid>>2
        int c = tid >> 2, io = (tid & 3) * 16;
        const float4* src = (const float4*)(x + ((size_t)n * CC + c) * WW_ +
                                            i0 + io);
#pragma unroll
        for (int q = 0; q < 4; q++) {
            float4 v = src[q];
            tl[c][io + q * 4 + 0] = f2bf(v.x);
            tl[c][io + q * 4 + 1] = f2bf(v.y);
            tl[c][io + q * 4 + 2] = f2bf(v.z);
            tl[c][io + q * 4 + 3] = f2bf(v.w);
        }
    }
    __syncthreads();
    {   // write XT row R = i0 + l + 64 with c-block swizzle key (R&7)
        int l = tid >> 2;
        int R = i0 + l + 64;
        int key = R & 7;
        u16* dst = XT + ((size_t)n * XTROWS + R) * 64;
        int pb0 = (tid & 3) * 2;
#pragma unroll
        for (int pq = 0; pq < 2; pq++) {
            int pb = pb0 + pq;
            int ch0 = (pb ^ key) << 3;
            bf16x8 v;
#pragma unroll
            for (int ci = 0; ci < 8; ci++) v[ci] = (short)tl[ch0 + ci][l];
            *(bf16x8*)(dst + pb * 8) = v;
        }
    }
}

// ---------- F2[f][w*64+c] = bf16(filt[f][c][w]) ----------
__global__ __launch_bounds__(256) void prep(const float* __restrict__ filt,
                                            u16* __restrict__ F2) {
    int idx = blockIdx.x * 256 + threadIdx.x;
    if (idx >= FF * 576) return;
    int f = idx / 576, wc = idx % 576;
    int w = wc >> 6, c = wc & 63;
    F2[idx] = f2bf(filt[((size_t)f * CC + c) * TAPS + w]);
}

// ---------- Dirichlet table D[t][j]: out[t] = sum_j z[j] D[t][j] -----------
// D = sin(7193*pi*a)/(N2*sin(pi*a)), a = (8192t - 7194(j-8))/P, exact-int
// phase; Taylor branch for tiny denominator; r==0 -> 7193/N2; j>=JMAX -> 0.
__global__ __launch_bounds__(256) void gen_D(u16* __restrict__ D) {
    int t = blockIdx.x;
    u32* row = (u32*)(D + (size_t)t * KD);
    for (int p = threadIdx.x; p < KD / 2; p += 256) {
        u32 pack = 0;
#pragma unroll
        for (int e = 0; e < 2; e++) {
            int j = 2 * p + e;
            float d = 0.f;
            if (j < JMAX) {
                long long v = 8192LL * t - 7194LL * (long long)(j - 8);
                long long r = v % PBIG;
                if (r < 0) r += PBIG;
                if (r == 0) {
                    d = 7193.0f / 7194.0f;
                } else {
                    long long n64 = (7193LL * r) % (2LL * PBIG);
                    float num = vsin((float)n64 * (float)(0.5 / (double)PBIG));
                    long long rr = (r < PBIG - r) ? r : PBIG - r;
                    float den;
                    if (rr < (1LL << 18))
                        den = (float)rr *
                              (float)(3.14159265358979323846 / (double)PBIG);
                    else
                        den = vsin((float)r * (float)(0.5 / (double)PBIG));
                    d = num / (7194.0f * den);
                }
            }
            pack |= (u32)f2bf(d) << (16 * e);
        }
        row[p] = pack;
    }
}

// ============ conv9: z[n*128+f][j] = sum_{c,w} filt[f,c,w]*xhat[j-8+w] =====
// A = F2 (128x576, dbuf per tap); B read DIRECT from staged x window
// (shift = tap), no Z materialization. Block (jt, n), 256 thr, 4 waves.
#define STAGE_A9(T, BUF)                                                    \
    _Pragma("unroll")                                                       \
    for (int q = 0; q < 4; q++) {                                           \
        gload16(F2 + (size_t)(wid * 32 + q * 8 + (lane >> 3)) * 576 +       \
                    (T) * 64 + (((lane & 7) ^ (lane >> 3)) * 8),            \
                lac + (BUF)*16384 + (wid * 32 + q * 8) * 128);              \
    }

__global__ __launch_bounds__(256, 2) void conv9(const u16* __restrict__ XT,
                                                const u16* __restrict__ F2,
                                                u16* __restrict__ Z) {
    __shared__ u16 la[2 * 128 * 64];   // 32 KB A dbuf
    __shared__ u16 lx[96 * 64];        // 12 KB x window (rows l, swz c-blk)
    const int tid = threadIdx.x;
    const int lane = tid & 63, wid = tid >> 6;
    const int jt = blockIdx.x, n = blockIdx.y;
    const int fr = lane & 15;
    const int hk = (lane >> 4) << 4;
    const int askew = (fr & 7) << 4;
    char* lac = (char*)la;
    char* lxc = (char*)lx;

    // stage x window: XT[n] rows jt*64+56 .. +151 (96 rows x 128B), linear.
    // local row l has key (l&7) == (R&7) since start row = 0 mod 8.
    {
        const u16* src = XT + ((size_t)n * XTROWS + jt * 64 + 56) * 64;
#pragma unroll
        for (int q = 0; q < 3; q++) {
            int off = (wid * 3 + q) * 512;   // u16 units
            gload16(src + off + lane * 8, lxc + off * 2);
        }
    }
    STAGE_A9(0, 0)
    __syncthreads();

    f32x4 acc[2][4];
#pragma unroll
    for (int i = 0; i < 2; i++)
#pragma unroll
        for (int j = 0; j < 4; j++) acc[i][j] = (f32x4){0.f, 0.f, 0.f, 0.f};

    bf16x8 af[2][2], bfr[4][2];
    for (int t = 0; t < TAPS; ++t) {
        const int cur = t & 1, nxt = cur ^ 1;
#pragma unroll
        for (int m2 = 0; m2 < 2; m2++)
#pragma unroll
            for (int kk = 0; kk < 2; kk++) {
                int row_ = wid * 32 + m2 * 16 + fr;
                af[m2][kk] = *(const bf16x8*)(lac + cur * 16384 + row_ * 128 +
                                              ((kk * 64 + hk) ^ askew));
            }
#pragma unroll
        for (int n4 = 0; n4 < 4; n4++)
#pragma unroll
            for (int kk = 0; kk < 2; kk++) {
                int l_ = n4 * 16 + fr + t;   // jl + tap shift
                bfr[n4][kk] = *(const bf16x8*)(lxc + l_ * 128 +
                                  ((kk * 64 + hk) ^ ((l_ & 7) << 4)));
            }
        if (t + 1 < TAPS) STAGE_A9(t + 1, nxt)
        __builtin_amdgcn_s_setprio(1);
#pragma unroll
        for (int kk = 0; kk < 2; kk++)
#pragma unroll
            for (int m2 = 0; m2 < 2; m2++)
#pragma unroll
                for (int n4 = 0; n4 < 4; n4++)
                    acc[m2][n4] = __builtin_amdgcn_mfma_f32_16x16x32_bf16(
                        af[m2][kk], bfr[n4][kk], acc[m2][n4], 0, 0, 0);
        __builtin_amdgcn_s_setprio(0);
        __syncthreads();
    }

    // epilogue: C/D layout col=lane&15, row=(lane>>4)*4+j  [m89]
#pragma unroll
    for (int m2 = 0; m2 < 2; m2++) {
#pragma unroll
        for (int n4 = 0; n4 < 4; n4++) {
            int colk = jt * 64 + n4 * 16 + fr;
            int f0 = wid * 32 + m2 * 16 + ((lane >> 4) << 2);
#pragma unroll
            for (int j = 0; j < 4; j++) {
                int sig2 = n * 128 + f0 + j;
                Z[(size_t)sig2 * KD + colk] = f2bf(acc[m2][n4][j]);
            }
        }
    }
}

// ============ 256x256 MFMA GEMM, 2-barrier/K-tile, 16x16x32 grain ==========
// r7/r11-exact schedule (known-good). MODE 1: f32 out + bias, col<OW guard.
#define MFMA_Q(AS, BS, MH, NH)                                              \
    __builtin_amdgcn_s_setprio(1);                                          \
    _Pragma("unroll")                                                       \
    for (int kk = 0; kk < 2; kk++)                                          \
        _Pragma("unroll")                                                   \
        for (int m4 = 0; m4 < 4; m4++)                                      \
            _Pragma("unroll")                                               \
            for (int n2 = 0; n2 < 2; n2++)                                  \
                acc[(MH)*4 + m4][(NH)*2 + n2] =                             \
                    __builtin_amdgcn_mfma_f32_16x16x32_bf16(                \
                        AS[m4][kk], BS[n2][kk],                             \
                        acc[(MH)*4 + m4][(NH)*2 + n2], 0, 0, 0);            \
    __builtin_amdgcn_s_setprio(0);

#define LOAD_A(AS, MH, BUF)                                                 \
    _Pragma("unroll")                                                       \
    for (int m4 = 0; m4 < 4; m4++)                                          \
        _Pragma("unroll")                                                   \
        for (int kk = 0; kk < 2; kk++) {                                    \
            int row_ = wr * 128 + (MH)*64 + m4 * 16 + fr;                   \
            AS[m4][kk] = *(const bf16x8*)(smem + (BUF)*32768 +              \
                          row_ * 128 + ((kk * 64 + hk) ^ askew));           \
        }

#define LOAD_B(BS, NH, BUF)                                                 \
    _Pragma("unroll")                                                       \
    for (int n2 = 0; n2 < 2; n2++)                                          \
        _Pragma("unroll")                                                   \
        for (int kk = 0; kk < 2; kk++) {                                    \
            int row_ = wc * 64 + (NH)*32 + n2 * 16 + fr;                    \
            BS[n2][kk] = *(const bf16x8*)(smem + 65536 + (BUF)*32768 +      \
                          row_ * 128 + ((kk * 64 + hk) ^ askew));           \
        }

#define STAGE(Q, R, BUF)                                                    \
    {                                                                       \
        const u16* g_ = ((R) < 2) ? gA : gB;                                \
        size_t ro_ = (size_t)((R)&1) * 128 * K;                             \
        int lb_ = (((R) < 2) ? 0 : 65536) + (BUF)*32768 +                   \
                  (((R)&1) * 128 + wid * 16) * 128;                         \
        gload16(g_ + ro_ + (Q)*64, smem + lb_);                             \
        gload16(g_ + ro_ + (size_t)8 * K + (Q)*64, smem + lb_ + 1024);      \
    }

#define BAR() __builtin_amdgcn_s_barrier()

template <int MODE>
__global__ __launch_bounds__(512, 1) void gemm256(const u16* __restrict__ A,
                                                  const u16* __restrict__ B,
                                                  int K, int gridN,
                                                  void* __restrict__ Out,
                                                  int ldo,
                                                  const float* __restrict__ bias) {
    extern __shared__ char smem[];
    const int tid = threadIdx.x;
    const int lane = tid & 63, wid = tid >> 6;
    const int wr = wid >> 2, wc = wid & 3;
    const int fr = lane & 15;
    const int hk = (lane >> 4) << 4;
    const int askew = (fr & 7) << 4;

    const int nwg = (int)gridDim.x, cpx = nwg >> 3;
    const int bid = (int)blockIdx.x;
    const int wg = (bid & 7) * cpx + (bid >> 3);
    const int tm = wg / gridN, tn = wg % gridN;
    const int NT = K >> 6;

    f32x4 acc[8][4];
#pragma unroll
    for (int i = 0; i < 8; i++)
#pragma unroll
        for (int j = 0; j < 4; j++) acc[i][j] = (f32x4){0.f, 0.f, 0.f, 0.f};

    const int srow = lane >> 3;
    const int scol = ((lane & 7) ^ srow) * 8;
    const u16* gA = A + (size_t)(tm * 256 + wid * 16 + srow) * K + scol;
    const u16* gB = B + (size_t)(tn * 256 + wid * 16 + srow) * K + scol;

    STAGE(0, 0, 0) STAGE(0, 1, 0) STAGE(0, 2, 0) STAGE(0, 3, 0)
    STAGE(1, 0, 1) STAGE(1, 1, 1)
    asm volatile("s_waitcnt vmcnt(4)" ::: "memory");
    BAR();

    bf16x8 a0[4][2], a1[4][2], b0[2][2], b1[2][2];
    for (int t = 0; t < NT; ++t) {
        const int cur = t & 1, nxt = cur ^ 1;
        LOAD_A(a0, 0, cur)
        LOAD_B(b0, 0, cur)
        LOAD_B(b1, 1, cur)
        if (t + 1 < NT) { STAGE(t + 1, 2, nxt) STAGE(t + 1, 3, nxt) }
        MFMA_Q(a0, b0, 0, 0)
        LOAD_A(a1, 1, cur)
        MFMA_Q(a0, b1, 0, 1)
        asm volatile("s_waitcnt lgkmcnt(0)" ::: "memory");
        __builtin_amdgcn_sched_barrier(0);
        BAR();
        if (t + 2 < NT) { STAGE(t + 2, 0, cur) STAGE(t + 2, 1, cur) }
        MFMA_Q(a1, b1, 1, 1)
        MFMA_Q(a1, b0, 1, 0)
        if (t + 2 < NT) {
            asm volatile("s_waitcnt vmcnt(4)" ::: "memory");
        } else if (t + 1 < NT) {
            asm volatile("s_waitcnt vmcnt(0)" ::: "memory");
        }
        BAR();
    }

#pragma unroll
    for (int m = 0; m < 8; m++) {
#pragma unroll
        for (int n = 0; n < 4; n++) {
            int col  = tn * 256 + wc * 64 + n * 16 + fr;
            int row0 = tm * 256 + wr * 128 + m * 16 + ((lane >> 4) << 2);
#pragma unroll
            for (int j = 0; j < 4; j++) {
                int grow = row0 + j;
                if (MODE == 0) {
                    ((u16*)Out)[(size_t)grow * ldo + col] = f2bf(acc[m][n][j]);
                } else {
                    if (col < OW) {
                        ((float*)Out)[(size_t)grow * OW + col] =
                            acc[m][n][j] + bias[grow & 127];
                    }
                }
            }
        }
    }
}

// ---------- launch ----------
extern "C" void kernel_launch(void* const* d_in, const int* in_sizes, int n_in,
                              void* d_out, int out_size, void* d_ws, size_t ws_size,
                              hipStream_t stream) {
    (void)in_sizes; (void)n_in; (void)out_size; (void)ws_size;
    const float* x    = (const float*)d_in[0];
    const float* filt = (const float*)d_in[1];
    const float* bias = (const float*)d_in[2];

    char* ws = (char*)d_ws;
    u16* XT = (u16*)(ws);                  // 32*4352*64*2 = 17,825,792 B
    u16* Z  = (u16*)(ws + 17825792);       // 4096*4160*2  = 34,078,720 B
    u16* Dt = (u16*)(ws + 51904512);       // 4096*4160*2  = 34,078,720 B
    u16* F2 = (u16*)(ws + 85983232);       // 128*576*2    = 147,456 B
    // total: 86,130,688 B

    hipFuncSetAttribute(reinterpret_cast<const void*>(gemm256<1>),
                        hipFuncAttributeMaxDynamicSharedMemorySize, 131072);

    hipMemsetAsync(XT, 0, (size_t)32 * XTROWS * 64 * 2, stream);
    cast_xt<<<dim3(64, 32), 256, 0, stream>>>(x, XT);
    prep<<<288, 256, 0, stream>>>(filt, F2);
    gen_D<<<SIG2, 256, 0, stream>>>(Dt);
    conv9<<<dim3(KD / 64, NB), 256, 0, stream>>>(XT, F2, Z);
    gemm256<1><<<16 * 16, 512, 131072, stream>>>(
        Z, Dt, KD, 16, d_out, OW, bias);
}

// Round 13
// 169.464 us; speedup vs baseline: 3.0131x; 1.1909x over previous
//
#include <hip/hip_runtime.h>
#include <hip/hip_bf16.h>

typedef unsigned short u16;
typedef unsigned int   u32;

using bf16x8 = __attribute__((ext_vector_type(8))) short;
using f32x4  = __attribute__((ext_vector_type(4))) float;

// ---------- constants ----------
#define NB    32      // batch
#define CC    64      // in channels
#define WW_   4096    // input width
#define FF    128     // out channels
#define TAPS  9
#define KBINS 3597    // half_compressed
#define N2    7194    // compress_fft_size
#define OW    4088    // out width
#define SIG2  4096    // N*F
#define JMAX  4104    // conv support: tau in [-8,4095], j = tau+8
#define KD    4160    // padded conv length (mult of 64)
#define XTROWS 4352   // 64 zero + 4096 data + 192 zero
#define PBIG  58933248   // 8192*7194 (< 2^31; 2*PBIG also < 2^31)

__device__ __forceinline__ u16 f2bf(float f) {
    u32 u = __float_as_uint(f);
    return (u16)((u + 0x7FFFu + ((u >> 16) & 1u)) >> 16);
}
// HW trig, input in REVOLUTIONS (ISA: D=sin(S0*2pi)), arg kept in [0,1)
__device__ __forceinline__ float vsin(float x) {
    float r; asm("v_sin_f32 %0, %1" : "=v"(r) : "v"(x)); return r;
}
__device__ __forceinline__ float vrcp(float x) {
    float r; asm("v_rcp_f32 %0, %1" : "=v"(r) : "v"(x)); return r;
}

// async global->LDS, 16B per lane; lds dest is wave-uniform base + lane*16
__device__ __forceinline__ void gload16(const void* g, void* l) {
    __builtin_amdgcn_global_load_lds(
        (const __attribute__((address_space(1))) void*)g,
        (__attribute__((address_space(3))) void*)l, 16, 0, 0);
}

// ---------- cast + transpose x into XT[n][R][c-swizzled] ----------
// XT row R = x col (R-64); mem pos pb*8+ci holds channel (pb^(R&7))*8+ci.
// v2: u32-packed LDS (2 bf16/word); blocks 64..67 write the zero-pad rows.
__global__ __launch_bounds__(256) void cast_xt(const float* __restrict__ x,
                                               u16* __restrict__ XT) {
    __shared__ u32 tl[64][33];          // [c][i2], +1 pad
    const int tid = threadIdx.x;
    const int it = blockIdx.x, n = blockIdx.y;
    if (it >= 64) {                     // zero rows: R in [0,64) U [4160,4352)
        int zb = it - 64;               // 0..3
        int i2 = tid >> 3, cb = tid & 7;
        bf16x8 z;
#pragma unroll
        for (int q = 0; q < 8; q++) z[q] = 0;
#pragma unroll
        for (int e = 0; e < 2; e++) {
            int zr = zb * 64 + 2 * i2 + e;
            int R = (zr < 64) ? zr : (4096 + zr);
            *(bf16x8*)(XT + ((size_t)n * XTROWS + R) * 64 + cb * 8) = z;
        }
        return;
    }
    const int i0 = it * 64;
    {   // write side: c = tid>>2, 16 consecutive i packed 2/word
        int c = tid >> 2, iq = tid & 3;
        const float4* src = (const float4*)(x + ((size_t)n * CC + c) * WW_ +
                                            i0 + iq * 16);
#pragma unroll
        for (int q = 0; q < 4; q++) {
            float4 v = src[q];
            tl[c][iq * 8 + q * 2]     = (u32)f2bf(v.x) | ((u32)f2bf(v.y) << 16);
            tl[c][iq * 8 + q * 2 + 1] = (u32)f2bf(v.z) | ((u32)f2bf(v.w) << 16);
        }
    }
    __syncthreads();
    {   // read side: one u32 per channel gives BOTH rows of the i-pair
        int i2 = tid >> 3, cb = tid & 7;
        int R0 = i0 + 64 + 2 * i2, R1 = R0 + 1;
        bf16x8 vlo, vhi;
#pragma unroll
        for (int ci = 0; ci < 8; ci++) {
            u32 w = tl[cb * 8 + ci][i2];
            vlo[ci] = (short)(u16)(w & 0xffffu);
            vhi[ci] = (short)(u16)(w >> 16);
        }
        *(bf16x8*)(XT + ((size_t)n * XTROWS + R0) * 64 +
                   ((cb ^ (R0 & 7)) * 8)) = vlo;
        *(bf16x8*)(XT + ((size_t)n * XTROWS + R1) * 64 +
                   ((cb ^ (R1 & 7)) * 8)) = vhi;
    }
}

// ---------- Dirichlet table D[t][j] + F2 prep (grid tail) ------------------
// D = sin(7193*pi*a)/(N2*sin(pi*a)), a = (8192t - 7194(j-8))/P.
// Division-free int32 phase: |v| < P -> r = v(+P); 7193r mod 2P =
// 7194*(r&16383) - r (+2P if <0), since 2P = 7194*16384.
__global__ __launch_bounds__(256) void gen_D(u16* __restrict__ D,
                                             const float* __restrict__ filt,
                                             u16* __restrict__ F2) {
    int b = blockIdx.x;
    if (b >= SIG2) {                   // F2[f][w*64+c] = bf16(filt[f][c][w])
        int idx = (b - SIG2) * 256 + threadIdx.x;
        if (idx < FF * 576) {
            int f = idx / 576, wc = idx % 576;
            int w = wc >> 6, c = wc & 63;
            F2[idx] = f2bf(filt[((size_t)f * CC + c) * TAPS + w]);
        }
        return;
    }
    const int t = b;
    const int base = 8192 * t;
    u32* row = (u32*)(D + (size_t)t * KD);
    for (int p = threadIdx.x; p < KD / 2; p += 256) {
        u32 pack = 0;
#pragma unroll
        for (int e = 0; e < 2; e++) {
            int j = 2 * p + e;
            float d = 0.f;
            if (j < JMAX) {
                int v = base - 7194 * (j - 8);
                int r = (v < 0) ? v + PBIG : v;
                if (r == 0) {
                    d = 7193.0f / 7194.0f;
                } else {
                    int m = 7194 * (r & 16383) - r;   // 7193r mod 2P
                    if (m < 0) m += 2 * PBIG;
                    float num = vsin((float)m * (float)(0.5 / (double)PBIG));
                    int rr = (r < PBIG - r) ? r : PBIG - r;
                    float den = (rr < (1 << 18))
                        ? (float)rr *
                          (float)(3.14159265358979323846 / (double)PBIG)
                        : vsin((float)r * (float)(0.5 / (double)PBIG));
                    d = num * vrcp(den) * (1.0f / 7194.0f);
                }
            }
            pack |= (u32)f2bf(d) << (16 * e);
        }
        row[p] = pack;
    }
}

// ============ conv9: z[n*128+f][j] = sum_{c,w} filt[f,c,w]*xhat[j-8+w] =====
// A = F2 (128x576, dbuf per tap); B read DIRECT from staged x window
// (shift = tap), no Z materialization. Block (jt, n), 256 thr, 4 waves.
#define STAGE_A9(T, BUF)                                                    \
    _Pragma("unroll")                                                       \
    for (int q = 0; q < 4; q++) {                                           \
        gload16(F2 + (size_t)(wid * 32 + q * 8 + (lane >> 3)) * 576 +       \
                    (T) * 64 + (((lane & 7) ^ (lane >> 3)) * 8),            \
                lac + (BUF)*16384 + (wid * 32 + q * 8) * 128);              \
    }

__global__ __launch_bounds__(256, 2) void conv9(const u16* __restrict__ XT,
                                                const u16* __restrict__ F2,
                                                u16* __restrict__ Z) {
    __shared__ u16 la[2 * 128 * 64];   // 32 KB A dbuf
    __shared__ u16 lx[96 * 64];        // 12 KB x window (rows l, swz c-blk)
    const int tid = threadIdx.x;
    const int lane = tid & 63, wid = tid >> 6;
    const int jt = blockIdx.x, n = blockIdx.y;
    const int fr = lane & 15;
    const int hk = (lane >> 4) << 4;
    const int askew = (fr & 7) << 4;
    char* lac = (char*)la;
    char* lxc = (char*)lx;

    // stage x window: XT[n] rows jt*64+56 .. +151 (96 rows x 128B), linear.
    {
        const u16* src = XT + ((size_t)n * XTROWS + jt * 64 + 56) * 64;
#pragma unroll
        for (int q = 0; q < 3; q++) {
            int off = (wid * 3 + q) * 512;   // u16 units
            gload16(src + off + lane * 8, lxc + off * 2);
        }
    }
    STAGE_A9(0, 0)
    __syncthreads();

    f32x4 acc[2][4];
#pragma unroll
    for (int i = 0; i < 2; i++)
#pragma unroll
        for (int j = 0; j < 4; j++) acc[i][j] = (f32x4){0.f, 0.f, 0.f, 0.f};

    bf16x8 af[2][2], bfr[4][2];
    for (int t = 0; t < TAPS; ++t) {
        const int cur = t & 1, nxt = cur ^ 1;
#pragma unroll
        for (int m2 = 0; m2 < 2; m2++)
#pragma unroll
            for (int kk = 0; kk < 2; kk++) {
                int row_ = wid * 32 + m2 * 16 + fr;
                af[m2][kk] = *(const bf16x8*)(lac + cur * 16384 + row_ * 128 +
                                              ((kk * 64 + hk) ^ askew));
            }
#pragma unroll
        for (int n4 = 0; n4 < 4; n4++)
#pragma unroll
            for (int kk = 0; kk < 2; kk++) {
                int l_ = n4 * 16 + fr + t;   // jl + tap shift
                bfr[n4][kk] = *(const bf16x8*)(lxc + l_ * 128 +
                                  ((kk * 64 + hk) ^ ((l_ & 7) << 4)));
            }
        if (t + 1 < TAPS) STAGE_A9(t + 1, nxt)
        __builtin_amdgcn_s_setprio(1);
#pragma unroll
        for (int kk = 0; kk < 2; kk++)
#pragma unroll
            for (int m2 = 0; m2 < 2; m2++)
#pragma unroll
                for (int n4 = 0; n4 < 4; n4++)
                    acc[m2][n4] = __builtin_amdgcn_mfma_f32_16x16x32_bf16(
                        af[m2][kk], bfr[n4][kk], acc[m2][n4], 0, 0, 0);
        __builtin_amdgcn_s_setprio(0);
        __syncthreads();
    }

    // epilogue: C/D layout col=lane&15, row=(lane>>4)*4+j  [m89]
#pragma unroll
    for (int m2 = 0; m2 < 2; m2++) {
#pragma unroll
        for (int n4 = 0; n4 < 4; n4++) {
            int colk = jt * 64 + n4 * 16 + fr;
            int f0 = wid * 32 + m2 * 16 + ((lane >> 4) << 2);
#pragma unroll
            for (int j = 0; j < 4; j++) {
                int sig2 = n * 128 + f0 + j;
                Z[(size_t)sig2 * KD + colk] = f2bf(acc[m2][n4][j]);
            }
        }
    }
}

// ============ 256x256 MFMA GEMM, 2-barrier/K-tile, 16x16x32 grain ==========
// r7/r11-exact schedule (known-good). MODE 1: f32 out + bias, col<OW guard.
#define MFMA_Q(AS, BS, MH, NH)                                              \
    __builtin_amdgcn_s_setprio(1);                                          \
    _Pragma("unroll")                                                       \
    for (int kk = 0; kk < 2; kk++)                                          \
        _Pragma("unroll")                                                   \
        for (int m4 = 0; m4 < 4; m4++)                                      \
            _Pragma("unroll")                                               \
            for (int n2 = 0; n2 < 2; n2++)                                  \
                acc[(MH)*4 + m4][(NH)*2 + n2] =                             \
                    __builtin_amdgcn_mfma_f32_16x16x32_bf16(                \
                        AS[m4][kk], BS[n2][kk],                             \
                        acc[(MH)*4 + m4][(NH)*2 + n2], 0, 0, 0);            \
    __builtin_amdgcn_s_setprio(0);

#define LOAD_A(AS, MH, BUF)                                                 \
    _Pragma("unroll")                                                       \
    for (int m4 = 0; m4 < 4; m4++)                                          \
        _Pragma("unroll")                                                   \
        for (int kk = 0; kk < 2; kk++) {                                    \
            int row_ = wr * 128 + (MH)*64 + m4 * 16 + fr;                   \
            AS[m4][kk] = *(const bf16x8*)(smem + (BUF)*32768 +              \
                          row_ * 128 + ((kk * 64 + hk) ^ askew));           \
        }

#define LOAD_B(BS, NH, BUF)                                                 \
    _Pragma("unroll")                                                       \
    for (int n2 = 0; n2 < 2; n2++)                                          \
        _Pragma("unroll")                                                   \
        for (int kk = 0; kk < 2; kk++) {                                    \
            int row_ = wc * 64 + (NH)*32 + n2 * 16 + fr;                    \
            BS[n2][kk] = *(const bf16x8*)(smem + 65536 + (BUF)*32768 +      \
                          row_ * 128 + ((kk * 64 + hk) ^ askew));           \
        }

#define STAGE(Q, R, BUF)                                                    \
    {                                                                       \
        const u16* g_ = ((R) < 2) ? gA : gB;                                \
        size_t ro_ = (size_t)((R)&1) * 128 * K;                             \
        int lb_ = (((R) < 2) ? 0 : 65536) + (BUF)*32768 +                   \
                  (((R)&1) * 128 + wid * 16) * 128;                         \
        gload16(g_ + ro_ + (Q)*64, smem + lb_);                             \
        gload16(g_ + ro_ + (size_t)8 * K + (Q)*64, smem + lb_ + 1024);      \
    }

#define BAR() __builtin_amdgcn_s_barrier()

template <int MODE>
__global__ __launch_bounds__(512, 1) void gemm256(const u16* __restrict__ A,
                                                  const u16* __restrict__ B,
                                                  int K, int gridN,
                                                  void* __restrict__ Out,
                                                  int ldo,
                                                  const float* __restrict__ bias) {
    extern __shared__ char smem[];
    const int tid = threadIdx.x;
    const int lane = tid & 63, wid = tid >> 6;
    const int wr = wid >> 2, wc = wid & 3;
    const int fr = lane & 15;
    const int hk = (lane >> 4) << 4;
    const int askew = (fr & 7) << 4;

    const int nwg = (int)gridDim.x, cpx = nwg >> 3;
    const int bid = (int)blockIdx.x;
    const int wg = (bid & 7) * cpx + (bid >> 3);
    const int tm = wg / gridN, tn = wg % gridN;
    const int NT = K >> 6;

    f32x4 acc[8][4];
#pragma unroll
    for (int i = 0; i < 8; i++)
#pragma unroll
        for (int j = 0; j < 4; j++) acc[i][j] = (f32x4){0.f, 0.f, 0.f, 0.f};

    const int srow = lane >> 3;
    const int scol = ((lane & 7) ^ srow) * 8;
    const u16* gA = A + (size_t)(tm * 256 + wid * 16 + srow) * K + scol;
    const u16* gB = B + (size_t)(tn * 256 + wid * 16 + srow) * K + scol;

    STAGE(0, 0, 0) STAGE(0, 1, 0) STAGE(0, 2, 0) STAGE(0, 3, 0)
    STAGE(1, 0, 1) STAGE(1, 1, 1)
    asm volatile("s_waitcnt vmcnt(4)" ::: "memory");
    BAR();

    bf16x8 a0[4][2], a1[4][2], b0[2][2], b1[2][2];
    for (int t = 0; t < NT; ++t) {
        const int cur = t & 1, nxt = cur ^ 1;
        LOAD_A(a0, 0, cur)
        LOAD_B(b0, 0, cur)
        LOAD_B(b1, 1, cur)
        if (t + 1 < NT) { STAGE(t + 1, 2, nxt) STAGE(t + 1, 3, nxt) }
        MFMA_Q(a0, b0, 0, 0)
        LOAD_A(a1, 1, cur)
        MFMA_Q(a0, b1, 0, 1)
        asm volatile("s_waitcnt lgkmcnt(0)" ::: "memory");
        __builtin_amdgcn_sched_barrier(0);
        BAR();
        if (t + 2 < NT) { STAGE(t + 2, 0, cur) STAGE(t + 2, 1, cur) }
        MFMA_Q(a1, b1, 1, 1)
        MFMA_Q(a1, b0, 1, 0)
        if (t + 2 < NT) {
            asm volatile("s_waitcnt vmcnt(4)" ::: "memory");
        } else if (t + 1 < NT) {
            asm volatile("s_waitcnt vmcnt(0)" ::: "memory");
        }
        BAR();
    }

#pragma unroll
    for (int m = 0; m < 8; m++) {
#pragma unroll
        for (int n = 0; n < 4; n++) {
            int col  = tn * 256 + wc * 64 + n * 16 + fr;
            int row0 = tm * 256 + wr * 128 + m * 16 + ((lane >> 4) << 2);
#pragma unroll
            for (int j = 0; j < 4; j++) {
                int grow = row0 + j;
                if (MODE == 0) {
                    ((u16*)Out)[(size_t)grow * ldo + col] = f2bf(acc[m][n][j]);
                } else {
                    if (col < OW) {
                        ((float*)Out)[(size_t)grow * OW + col] =
                            acc[m][n][j] + bias[grow & 127];
                    }
                }
            }
        }
    }
}

// ---------- launch ----------
extern "C" void kernel_launch(void* const* d_in, const int* in_sizes, int n_in,
                              void* d_out, int out_size, void* d_ws, size_t ws_size,
                              hipStream_t stream) {
    (void)in_sizes; (void)n_in; (void)out_size; (void)ws_size;
    const float* x    = (const float*)d_in[0];
    const float* filt = (const float*)d_in[1];
    const float* bias = (const float*)d_in[2];

    char* ws = (char*)d_ws;
    u16* XT = (u16*)(ws);                  // 32*4352*64*2 = 17,825,792 B
    u16* Z  = (u16*)(ws + 17825792);       // 4096*4160*2  = 34,078,720 B
    u16* Dt = (u16*)(ws + 51904512);       // 4096*4160*2  = 34,078,720 B
    u16* F2 = (u16*)(ws + 85983232);       // 128*576*2    = 147,456 B
    // total: 86,130,688 B

    hipFuncSetAttribute(reinterpret_cast<const void*>(gemm256<1>),
                        hipFuncAttributeMaxDynamicSharedMemorySize, 131072);

    cast_xt<<<dim3(68, 32), 256, 0, stream>>>(x, XT);
    gen_D<<<SIG2 + 288, 256, 0, stream>>>(Dt, filt, F2);
    conv9<<<dim3(KD / 64, NB), 256, 0, stream>>>(XT, F2, Z);
    gemm256<1><<<16 * 16, 512, 131072, stream>>>(
        Z, Dt, KD, 16, d_out, OW, bias);
}